// Round 2
// baseline (9797.163 us; speedup 1.0000x reference)
//
#include <hip/hip_runtime.h>
#include <math.h>

// ---------------- problem constants ----------------
// B=32 (8 chunks of 4), L=244, C=128, F=64, KS=5
// conv lengths: 244 -> 240 -> 236 -> 232 -> 228 ; S=76 ; F3=192 ; D_SA=64
// HID=512, 3*HID=1536, K_big = 64*128 = 8192
// Workspace budget: ~112 MB (see kernel_launch offsets)

__device__ inline float sigm(float x){ return 1.f/(1.f+__expf(-x)); }

// ---------------- conv1: (B,1,L,C) -> (4,64,240,128), relu ----------------
__global__ __launch_bounds__(256) void conv1_k(const float* __restrict__ x,
        float* __restrict__ out, const float* __restrict__ w1,
        const float* __restrict__ b1, int b_base)
{
    int i = blockIdx.x*256 + threadIdx.x;       // < 4*64*240*128
    int c = i & 127; int t2 = i >> 7;
    int l = t2 % 240; int t3 = t2 / 240;
    int f = t3 & 63;  int b = t3 >> 6;          // b in 0..3
    const float* xp = x + ((size_t)(b_base + b)*244 + l)*128 + c;
    float acc = 0.f;
    #pragma unroll
    for (int k=0;k<5;++k) acc += w1[f*5+k]*xp[k*128];
    acc += b1[f];
    out[i] = acc > 0.f ? acc : 0.f;
}

// ---------------- conv2/3/4: (4,64,Lin,128)->(4,64,Lout,128), relu --------
// block 256 = 128c x 2 f-halves; each thread: 8 f x 2 l outputs
__global__ __launch_bounds__(256) void conv_k(const float* __restrict__ in,
        float* __restrict__ out, const float* __restrict__ w,
        const float* __restrict__ bias, int Lin, int Lout)
{
    __shared__ float wlds[16*64*5];
    int t = threadIdx.x;
    int f0 = blockIdx.y * 16;
    for (int idx = t; idx < 5120; idx += 256){
        int fl = idx & 15; int rest = idx >> 4; int k = rest % 5; int fi = rest / 5;
        wlds[(fi*5 + k)*16 + fl] = w[((f0 + fl)*64 + fi)*5 + k];
    }
    __syncthreads();
    int c  = t & 127;
    int fh = t >> 7;            // 0/1
    int l0 = blockIdx.x * 2;
    int b  = blockIdx.z;
    float acc[2][8];
    #pragma unroll
    for (int li=0; li<2; ++li)
        #pragma unroll
        for (int j=0;j<8;++j) acc[li][j]=0.f;
    const float* ip = in + (size_t)b*64*Lin*128 + l0*128 + c;
    for (int fi = 0; fi < 64; ++fi){
        float xv[6];
        #pragma unroll
        for (int p=0;p<6;++p) xv[p] = ip[p*128];
        #pragma unroll
        for (int k=0;k<5;++k){
            float wv[8];
            *(float4*)&wv[0] = *(const float4*)&wlds[(fi*5+k)*16 + fh*8];
            *(float4*)&wv[4] = *(const float4*)&wlds[(fi*5+k)*16 + fh*8 + 4];
            #pragma unroll
            for (int j=0;j<8;++j){
                acc[0][j] += wv[j]*xv[k];
                acc[1][j] += wv[j]*xv[k+1];
            }
        }
        ip += (size_t)Lin*128;
    }
    #pragma unroll
    for (int j=0;j<8;++j){
        int fo = f0 + fh*8 + j;
        float bv = bias[fo];
        #pragma unroll
        for (int li=0;li<2;++li){
            float v = acc[li][j] + bv;
            v = v > 0.f ? v : 0.f;
            out[(((size_t)b*64 + fo)*Lout + l0+li)*128 + c] = v;
        }
    }
}

// ---------------- repack attention weights: wrep[fj][m*64+d] = W_m[d][fj] --
__global__ __launch_bounds__(256) void repack_w_k(const float* __restrict__ wq,
        const float* __restrict__ wk, const float* __restrict__ wv,
        const float* __restrict__ wv1, float* __restrict__ wrep)
{
    int idx = blockIdx.x*256 + threadIdx.x;   // < 192*256
    int fj = idx >> 8, rest = idx & 255, m = rest >> 6, d = rest & 63;
    const float* src = (m==0)? wq : (m==1)? wk : (m==2)? wv : wv1;
    wrep[idx] = src[d*192 + fj];
}

// ---------------- projection: per (b,s) compute F,G,V,V1 (64x128 each) ----
// block 1024 = 128c x 8 dq ; thread: 8 d x 4 mats accumulators
__global__ __launch_bounds__(1024) void project_k(const float* __restrict__ h4,
        const float* __restrict__ wrep, float* __restrict__ Fo,
        float* __restrict__ Go, float* __restrict__ Vo, float* __restrict__ V1o)
{
    __shared__ float xs[96*128];
    int t = threadIdx.x;
    int s = blockIdx.x, bl = blockIdx.y;
    int c = t & 127, dq = t >> 7;           // dq in 0..7
    float acc[4][8];
    #pragma unroll
    for (int m=0;m<4;++m)
        #pragma unroll
        for (int j=0;j<8;++j) acc[m][j]=0.f;

    for (int half=0; half<2; ++half){
        __syncthreads();
        #pragma unroll
        for (int it=0; it<12; ++it){
            int r = it*8 + dq;
            int fj = half*96 + r;
            int f = fj/3, jj = fj - f*3;
            xs[r*128 + c] = h4[(((size_t)bl*64 + f)*228 + 3*s + jj)*128 + c];
        }
        __syncthreads();
        for (int r=0; r<96; ++r){
            float xv = xs[r*128 + c];
            const float* wp = wrep + (half*96 + r)*256 + dq*8;
            #pragma unroll
            for (int m=0;m<4;++m){
                float4 wa = *(const float4*)(wp + m*64);
                float4 wb = *(const float4*)(wp + m*64 + 4);
                acc[m][0]+=wa.x*xv; acc[m][1]+=wa.y*xv; acc[m][2]+=wa.z*xv; acc[m][3]+=wa.w*xv;
                acc[m][4]+=wb.x*xv; acc[m][5]+=wb.y*xv; acc[m][6]+=wb.z*xv; acc[m][7]+=wb.w*xv;
            }
        }
    }
    size_t base = (((size_t)bl*76 + s)*64)*128;
    float* outs_[4] = {Fo,Go,Vo,V1o};
    #pragma unroll
    for (int m=0;m<4;++m)
        #pragma unroll
        for (int jd=0;jd<8;++jd)
            outs_[m][base + (size_t)(dq*8+jd)*128 + c] = acc[m][jd];
}

// ---------------- attention, 64KB static LDS -------------------------------
// phase 1: sm[0..8192)=F, sm[8192..16384)=G -> scores in regs
// phase 2: red in sm[0..256); V loaded into sm[8192..16384)
// phase 3: beta halves into sm[0..8192), two PV partial passes
__global__ __launch_bounds__(256) void attend_k(const float* __restrict__ Fg,
        const float* __restrict__ Gg, const float* __restrict__ Vg,
        const float* __restrict__ V1g, const float* __restrict__ gamma,
        float* __restrict__ seqc)
{
    __shared__ float sm[16384];    // exactly 64 KB
    int t = threadIdx.x;
    int s = blockIdx.x, bl = blockIdx.y;
    size_t base = (((size_t)bl*76 + s)*64)*128;
    for (int i=t; i<8192; i+=256) sm[i]      = Fg[base+i];
    for (int i=t; i<8192; i+=256) sm[8192+i] = Gg[base+i];
    __syncthreads();

    int k = t & 127, ch = t >> 7;
    float sc[64];
    #pragma unroll
    for (int j=0;j<64;++j) sc[j]=0.f;
    for (int d=0; d<64; ++d){
        float gk = sm[8192 + d*128 + k];
        #pragma unroll
        for (int cj=0; cj<16; ++cj){
            float4 f4 = *(const float4*)&sm[d*128 + ch*64 + cj*4];
            sc[cj*4+0] += f4.x*gk; sc[cj*4+1] += f4.y*gk;
            sc[cj*4+2] += f4.z*gk; sc[cj*4+3] += f4.w*gk;
        }
    }
    __syncthreads();                       // F,G now dead
    float m = -1e30f;
    #pragma unroll
    for (int j=0;j<64;++j) m = fmaxf(m, sc[j]);
    sm[t] = m;                              // red region sm[0..256)
    // load V into dead G region
    for (int i=t; i<8192; i+=256) sm[8192+i] = Vg[base+i];
    __syncthreads();
    m = fmaxf(sm[k], sm[128+k]);
    float lsum = 0.f;
    #pragma unroll
    for (int j=0;j<64;++j){ sc[j] = __expf(sc[j]-m); lsum += sc[j]; }
    __syncthreads();
    sm[t] = lsum;
    __syncthreads();
    float rinv = 1.f/(sm[k] + sm[128+k]);
    #pragma unroll
    for (int j=0;j<64;++j) sc[j] *= rinv;
    __syncthreads();                        // red reads done

    // beta half 0 (c in [0,64)): written by ch==0 threads
    if (ch == 0){
        #pragma unroll
        for (int j=0;j<64;++j) sm[j*128 + k] = sc[j];
    }
    __syncthreads();

    int k2 = t & 31, dq = t >> 5;           // dq 0..7
    float ao[8][4];
    #pragma unroll
    for (int j=0;j<8;++j)
        #pragma unroll
        for (int mm=0;mm<4;++mm) ao[j][mm]=0.f;

    for (int c2=0; c2<64; ++c2){
        float bv0 = sm[c2*128 + k2],    bv1 = sm[c2*128 + k2+32];
        float bv2 = sm[c2*128 + k2+64], bv3 = sm[c2*128 + k2+96];
        #pragma unroll
        for (int j=0;j<8;++j){
            float v = sm[8192 + (dq*8+j)*128 + c2];
            ao[j][0]+=v*bv0; ao[j][1]+=v*bv1; ao[j][2]+=v*bv2; ao[j][3]+=v*bv3;
        }
    }
    __syncthreads();
    // beta half 1 (c in [64,128)): written by ch==1 threads
    if (ch == 1){
        #pragma unroll
        for (int j=0;j<64;++j) sm[j*128 + k] = sc[j];
    }
    __syncthreads();
    for (int c2=64; c2<128; ++c2){
        float bv0 = sm[(c2-64)*128 + k2],    bv1 = sm[(c2-64)*128 + k2+32];
        float bv2 = sm[(c2-64)*128 + k2+64], bv3 = sm[(c2-64)*128 + k2+96];
        #pragma unroll
        for (int j=0;j<8;++j){
            float v = sm[8192 + (dq*8+j)*128 + c2];
            ao[j][0]+=v*bv0; ao[j][1]+=v*bv1; ao[j][2]+=v*bv2; ao[j][3]+=v*bv3;
        }
    }

    float gm = gamma[0];
    size_t sbase = ((size_t)s*4 + bl)*8192;          // per-chunk row (s, b_local)
    #pragma unroll
    for (int j=0;j<8;++j){
        int d = dq*8+j;
        #pragma unroll
        for (int mm=0;mm<4;++mm){
            int kk = k2 + 32*mm;
            seqc[sbase + (size_t)d*128 + kk] = gm*ao[j][mm] + V1g[base + (size_t)d*128 + kk];
        }
    }
}

// ---------------- per-chunk GEMM: xg rows for 304 (s,b_local) rows ---------
__global__ __launch_bounds__(256) void gemm_xg(const float* __restrict__ A,
        const float* __restrict__ Bw, const float* __restrict__ bih,
        float* __restrict__ out, int b_base)
{
    __shared__ float As[32*68], Bs[32*68];
    int t = threadIdx.x;
    int row0 = blockIdx.y*64, g0 = blockIdx.x*64;
    int rl = t >> 2, kq = t & 3;
    int tx = t & 15, ty = t >> 4;
    float acc[4][4];
    #pragma unroll
    for (int p=0;p<4;++p)
        #pragma unroll
        for (int q=0;q<4;++q) acc[p][q]=0.f;
    for (int kt=0; kt<256; ++kt){
        int k0 = kt*32;
        float4 a0 = *(const float4*)&A [(size_t)(row0+rl)*8192 + k0 + kq*8];
        float4 a1 = *(const float4*)&A [(size_t)(row0+rl)*8192 + k0 + kq*8 + 4];
        float4 b0 = *(const float4*)&Bw[(size_t)(g0  +rl)*8192 + k0 + kq*8];
        float4 b1 = *(const float4*)&Bw[(size_t)(g0  +rl)*8192 + k0 + kq*8 + 4];
        __syncthreads();
        As[(kq*8+0)*68+rl]=a0.x; As[(kq*8+1)*68+rl]=a0.y; As[(kq*8+2)*68+rl]=a0.z; As[(kq*8+3)*68+rl]=a0.w;
        As[(kq*8+4)*68+rl]=a1.x; As[(kq*8+5)*68+rl]=a1.y; As[(kq*8+6)*68+rl]=a1.z; As[(kq*8+7)*68+rl]=a1.w;
        Bs[(kq*8+0)*68+rl]=b0.x; Bs[(kq*8+1)*68+rl]=b0.y; Bs[(kq*8+2)*68+rl]=b0.z; Bs[(kq*8+3)*68+rl]=b0.w;
        Bs[(kq*8+4)*68+rl]=b1.x; Bs[(kq*8+5)*68+rl]=b1.y; Bs[(kq*8+6)*68+rl]=b1.z; Bs[(kq*8+7)*68+rl]=b1.w;
        __syncthreads();
        #pragma unroll
        for (int kk=0;kk<32;++kk){
            float4 av = *(const float4*)&As[kk*68 + ty*4];
            float4 bv = *(const float4*)&Bs[kk*68 + tx*4];
            float a_[4] = {av.x,av.y,av.z,av.w};
            float b_[4] = {bv.x,bv.y,bv.z,bv.w};
            #pragma unroll
            for (int p=0;p<4;++p)
                #pragma unroll
                for (int q=0;q<4;++q) acc[p][q] += a_[p]*b_[q];
        }
    }
    float4 bi = *(const float4*)&bih[g0 + tx*4];
    float bi_[4] = {bi.x,bi.y,bi.z,bi.w};
    #pragma unroll
    for (int p=0;p<4;++p){
        int r = row0 + ty*4 + p;
        if (r < 304){
            int s = r >> 2, blc = r & 3;
            int orow = s*32 + b_base + blc;
            float4 o;
            o.x = acc[p][0]+bi_[0]; o.y = acc[p][1]+bi_[1];
            o.z = acc[p][2]+bi_[2]; o.w = acc[p][3]+bi_[3];
            *(float4*)&out[(size_t)orow*1536 + g0 + tx*4] = o;
        }
    }
}

// ---------------- GRU weight repack: whh_p[i][j] = {Wr[j][i],Wz[j][i],Wn[j][i],0}
__global__ __launch_bounds__(256) void build_whhp_k(const float* __restrict__ whh,
        float4* __restrict__ whh_p)
{
    int idx = blockIdx.x*256 + threadIdx.x;   // < 512*512
    int i = idx >> 9, j = idx & 511;
    float4 o;
    o.x = whh[(size_t)j*512 + i];
    o.y = whh[(size_t)(512+j)*512 + i];
    o.z = whh[(size_t)(1024+j)*512 + i];
    o.w = 0.f;
    whh_p[idx] = o;
}

// ---------------- one GRU step: 64 blocks (8 j-chunks x 8 b-quads) ---------
__global__ __launch_bounds__(256) void gru_step_k(const float4* __restrict__ whh_p,
        const float* __restrict__ xg, const float* __restrict__ bhh,
        float* __restrict__ outs, int s)
{
    __shared__ float hl[2048];
    int t = threadIdx.x;
    int jc = blockIdx.x & 7, bq = blockIdx.x >> 3;
    for (int idx=t; idx<2048; idx+=256)
        hl[idx] = outs[(size_t)s*16384 + (size_t)(bq*4 + (idx>>9))*512 + (idx&511)];
    __syncthreads();
    int j = jc*64 + (t & 63), bl_ = t >> 6, b = bq*4 + bl_;
    float a0=0.f,a1=0.f,a2=0.f;
    const float4* wp = whh_p + j;
    const float* hb = hl + bl_*512;
    #pragma unroll 4
    for (int i=0;i<512;++i){
        float4 w4 = wp[(size_t)i*512];
        float hv = hb[i];
        a0 += w4.x*hv; a1 += w4.y*hv; a2 += w4.z*hv;
    }
    size_t xi = (size_t)(s*32 + b)*1536 + j;
    float xr = xg[xi], xz = xg[xi+512], xn = xg[xi+1024];
    float hr = a0 + bhh[j], hz = a1 + bhh[512+j], hn = a2 + bhh[1024+j];
    float r = sigm(xr+hr), z = sigm(xz+hz);
    float n = tanhf(xn + r*hn);
    float hp = hb[j];
    float hnew = (1.f - z)*n + z*hp;
    outs[(size_t)(s+1)*16384 + (size_t)b*512 + j] = hnew;
}

// ---------------- final attention pooling over s ---------------------------
__global__ __launch_bounds__(256) void pool_k(const float* __restrict__ outs,
        const float* __restrict__ fcw, const float* __restrict__ fcb,
        float* __restrict__ out)
{
    __shared__ float att[80], watt[128];
    int b = blockIdx.x, t = threadIdx.x;
    int w = t >> 6, lane = t & 63;
    for (int s = w; s < 76; s += 4){
        float acc = 0.f;
        const float* op = outs + (size_t)(s+1)*16384 + (size_t)b*512;
        #pragma unroll
        for (int hh = 0; hh < 512; hh += 64) acc += op[hh+lane]*fcw[hh+lane];
        #pragma unroll
        for (int off=32; off; off>>=1) acc += __shfl_down(acc, off);
        if (lane==0) att[s] = acc + fcb[0];
    }
    __syncthreads();
    if (t < 64){
        float a0 = (t<76)? att[t] : -1e30f;
        float a1 = (t+64<76)? att[t+64] : -1e30f;
        float m = fmaxf(a0,a1);
        #pragma unroll
        for (int off=32; off; off>>=1) m = fmaxf(m, __shfl_xor(m, off));
        float e0 = (t<76)? __expf(a0-m) : 0.f;
        float e1 = (t+64<76)? __expf(a1-m) : 0.f;
        float ssum = e0+e1;
        #pragma unroll
        for (int off=32; off; off>>=1) ssum += __shfl_xor(ssum, off);
        float ri = 1.f/ssum;
        watt[t] = e0*ri;
        watt[t+64] = e1*ri;
    }
    __syncthreads();
    for (int h = t; h < 512; h += 256){
        float acc=0.f;
        for (int s=0;s<76;++s) acc += watt[s]*outs[(size_t)(s+1)*16384 + (size_t)b*512 + h];
        out[(size_t)b*512 + h] = acc;
    }
}

// ---------------- launch ----------------------------------------------------
extern "C" void kernel_launch(void* const* d_in, const int* in_sizes, int n_in,
                              void* d_out, int out_size, void* d_ws, size_t ws_size,
                              hipStream_t stream)
{
    const float* x   = (const float*)d_in[0];
    const float* w1  = (const float*)d_in[1];  const float* b1  = (const float*)d_in[2];
    const float* w2  = (const float*)d_in[3];  const float* b2  = (const float*)d_in[4];
    const float* w3  = (const float*)d_in[5];  const float* b3  = (const float*)d_in[6];
    const float* w4  = (const float*)d_in[7];  const float* b4  = (const float*)d_in[8];
    const float* wq  = (const float*)d_in[9];  const float* wk  = (const float*)d_in[10];
    const float* wv  = (const float*)d_in[11]; const float* wv1 = (const float*)d_in[12];
    const float* gamma = (const float*)d_in[13];
    const float* wih = (const float*)d_in[14]; const float* whh = (const float*)d_in[15];
    const float* bih = (const float*)d_in[16]; const float* bhh = (const float*)d_in[17];
    const float* fcw = (const float*)d_in[18]; const float* fcb = (const float*)d_in[19];

    // workspace layout (floats); total 29,294,592 floats = 111.8 MiB
    float* ws = (float*)d_ws;
    size_t off = 0;
    float* bufA = ws + off; off += 7864320ull;    // 4*64*240*128 (also seqc: 304*8192)
    float* bufB = ws + off; off += 7733248ull;    // 4*64*236*128 (also F|G)
    float* bufC = ws + off; off += 7602176ull;    // 4*64*232*128 (also V|V1)
    float* xg   = ws + off; off += 3735552ull;    // 76*32*1536
    float* outs = ws + off; off += 77ull*16384;   // (76+1)*32*512
    float* wrep = ws + off; off += 49152ull;      // 192*256
    float4* whh_p = (float4*)(ws + off); off += 4ull*262144; // 512*512 float4

    repack_w_k<<<192, 256, 0, stream>>>(wq, wk, wv, wv1, wrep);
    build_whhp_k<<<1024, 256, 0, stream>>>(whh, whh_p);
    hipMemsetAsync(outs, 0, 16384*sizeof(float), stream);

    float* Fb  = bufB;
    float* Gb  = bufB + 2490368ull;   // 4*76*64*128
    float* Vb  = bufC;
    float* V1b = bufC + 2490368ull;

    for (int chunk=0; chunk<8; ++chunk){
        int b_base = chunk*4;
        conv1_k<<<30720, 256, 0, stream>>>(x, bufA, w1, b1, b_base);
        conv_k<<<dim3(118,4,4), 256, 0, stream>>>(bufA, bufB, w2, b2, 240, 236);
        conv_k<<<dim3(116,4,4), 256, 0, stream>>>(bufB, bufC, w3, b3, 236, 232);
        conv_k<<<dim3(114,4,4), 256, 0, stream>>>(bufC, bufA, w4, b4, 232, 228);
        project_k<<<dim3(76,4), 1024, 0, stream>>>(bufA, wrep, Fb, Gb, Vb, V1b);
        // attention writes per-chunk seq rows over dead h4 (bufA)
        attend_k<<<dim3(76,4), 256, 0, stream>>>(Fb, Gb, Vb, V1b, gamma, bufA);
        gemm_xg<<<dim3(24,5), 256, 0, stream>>>(bufA, wih, bih, xg, b_base);
    }
    for (int s=0; s<76; ++s)
        gru_step_k<<<64, 256, 0, stream>>>(whh_p, xg, bhh, outs, s);
    pool_k<<<32, 256, 0, stream>>>(outs, fcw, fcb, (float*)d_out);
}

// Round 3
// 7779.158 us; speedup vs baseline: 1.2594x; 1.2594x over previous
//
#include <hip/hip_runtime.h>
#include <math.h>

// ---------------- problem constants ----------------
// B=32 (16 chunks of 2), L=244, C=128, F=64, KS=5
// conv lengths: 244 -> 240 -> 236 -> 232 -> 228 ; S=76 ; F3=192 ; D_SA=64
// HID=512, 3*HID=1536, K_big = 64*128 = 8192 ; M_big = 76*32 = 2432
// Workspace: 105.5 MB (< proven-safe 111.8 MB)

typedef __attribute__((ext_vector_type(8))) short short8;
typedef __attribute__((ext_vector_type(4))) float f32x4;

__device__ inline float sigm(float x){ return 1.f/(1.f+__expf(-x)); }
__device__ inline unsigned short f2bf(float f){
    unsigned int u = __float_as_uint(f);
    u = (u + 0x7FFFu + ((u >> 16) & 1u)) >> 16;
    return (unsigned short)u;
}

// ---------------- conv1: (B,1,L,C) -> (2,64,240,128), relu ----------------
__global__ __launch_bounds__(256) void conv1_k(const float* __restrict__ x,
        float* __restrict__ out, const float* __restrict__ w1,
        const float* __restrict__ b1, int b_base)
{
    int i = blockIdx.x*256 + threadIdx.x;       // < 2*64*240*128
    int c = i & 127; int t2 = i >> 7;
    int l = t2 % 240; int t3 = t2 / 240;
    int f = t3 & 63;  int b = t3 >> 6;          // b in 0..1
    const float* xp = x + ((size_t)(b_base + b)*244 + l)*128 + c;
    float acc = 0.f;
    #pragma unroll
    for (int k=0;k<5;++k) acc += w1[f*5+k]*xp[k*128];
    acc += b1[f];
    out[i] = acc > 0.f ? acc : 0.f;
}

// ---------------- conv2/3/4: (2,64,Lin,128)->(2,64,Lout,128), relu --------
__global__ __launch_bounds__(256) void conv_k(const float* __restrict__ in,
        float* __restrict__ out, const float* __restrict__ w,
        const float* __restrict__ bias, int Lin, int Lout)
{
    __shared__ float wlds[16*64*5];
    int t = threadIdx.x;
    int f0 = blockIdx.y * 16;
    for (int idx = t; idx < 5120; idx += 256){
        int fl = idx & 15; int rest = idx >> 4; int k = rest % 5; int fi = rest / 5;
        wlds[(fi*5 + k)*16 + fl] = w[((f0 + fl)*64 + fi)*5 + k];
    }
    __syncthreads();
    int c  = t & 127;
    int fh = t >> 7;            // 0/1
    int l0 = blockIdx.x * 2;
    int b  = blockIdx.z;
    float acc[2][8];
    #pragma unroll
    for (int li=0; li<2; ++li)
        #pragma unroll
        for (int j=0;j<8;++j) acc[li][j]=0.f;
    const float* ip = in + (size_t)b*64*Lin*128 + l0*128 + c;
    for (int fi = 0; fi < 64; ++fi){
        float xv[6];
        #pragma unroll
        for (int p=0;p<6;++p) xv[p] = ip[p*128];
        #pragma unroll
        for (int k=0;k<5;++k){
            float wv[8];
            *(float4*)&wv[0] = *(const float4*)&wlds[(fi*5+k)*16 + fh*8];
            *(float4*)&wv[4] = *(const float4*)&wlds[(fi*5+k)*16 + fh*8 + 4];
            #pragma unroll
            for (int j=0;j<8;++j){
                acc[0][j] += wv[j]*xv[k];
                acc[1][j] += wv[j]*xv[k+1];
            }
        }
        ip += (size_t)Lin*128;
    }
    #pragma unroll
    for (int j=0;j<8;++j){
        int fo = f0 + fh*8 + j;
        float bv = bias[fo];
        #pragma unroll
        for (int li=0;li<2;++li){
            float v = acc[li][j] + bv;
            v = v > 0.f ? v : 0.f;
            out[(((size_t)b*64 + fo)*Lout + l0+li)*128 + c] = v;
        }
    }
}

// ---------------- repack attention weights: wrep[fj][m*64+d] = W_m[d][fj] --
__global__ __launch_bounds__(256) void repack_w_k(const float* __restrict__ wq,
        const float* __restrict__ wk, const float* __restrict__ wv,
        const float* __restrict__ wv1, float* __restrict__ wrep)
{
    int idx = blockIdx.x*256 + threadIdx.x;   // < 192*256
    int fj = idx >> 8, rest = idx & 255, m = rest >> 6, d = rest & 63;
    const float* src = (m==0)? wq : (m==1)? wk : (m==2)? wv : wv1;
    wrep[idx] = src[d*192 + fj];
}

// ---------------- projection: per (b,s) compute F,G,V,V1 (64x128 each) ----
__global__ __launch_bounds__(1024) void project_k(const float* __restrict__ h4,
        const float* __restrict__ wrep, float* __restrict__ Fo,
        float* __restrict__ Go, float* __restrict__ Vo, float* __restrict__ V1o)
{
    __shared__ float xs[96*128];
    int t = threadIdx.x;
    int s = blockIdx.x, bl = blockIdx.y;
    int c = t & 127, dq = t >> 7;           // dq in 0..7
    float acc[4][8];
    #pragma unroll
    for (int m=0;m<4;++m)
        #pragma unroll
        for (int j=0;j<8;++j) acc[m][j]=0.f;

    for (int half=0; half<2; ++half){
        __syncthreads();
        #pragma unroll
        for (int it=0; it<12; ++it){
            int r = it*8 + dq;
            int fj = half*96 + r;
            int f = fj/3, jj = fj - f*3;
            xs[r*128 + c] = h4[(((size_t)bl*64 + f)*228 + 3*s + jj)*128 + c];
        }
        __syncthreads();
        for (int r=0; r<96; ++r){
            float xv = xs[r*128 + c];
            const float* wp = wrep + (half*96 + r)*256 + dq*8;
            #pragma unroll
            for (int m=0;m<4;++m){
                float4 wa = *(const float4*)(wp + m*64);
                float4 wb = *(const float4*)(wp + m*64 + 4);
                acc[m][0]+=wa.x*xv; acc[m][1]+=wa.y*xv; acc[m][2]+=wa.z*xv; acc[m][3]+=wa.w*xv;
                acc[m][4]+=wb.x*xv; acc[m][5]+=wb.y*xv; acc[m][6]+=wb.z*xv; acc[m][7]+=wb.w*xv;
            }
        }
    }
    size_t base = (((size_t)bl*76 + s)*64)*128;
    float* outs_[4] = {Fo,Go,Vo,V1o};
    #pragma unroll
    for (int m=0;m<4;++m)
        #pragma unroll
        for (int jd=0;jd<8;++jd)
            outs_[m][base + (size_t)(dq*8+jd)*128 + c] = acc[m][jd];
}

// ---------------- attention, 64KB static LDS; writes seq row in bf16 ------
__global__ __launch_bounds__(256) void attend_k(const float* __restrict__ Fg,
        const float* __restrict__ Gg, const float* __restrict__ Vg,
        const float* __restrict__ V1g, const float* __restrict__ gamma,
        unsigned short* __restrict__ seq_bf, int b_base)
{
    __shared__ float sm[16384];    // exactly 64 KB
    int t = threadIdx.x;
    int s = blockIdx.x, bl = blockIdx.y;
    size_t base = (((size_t)bl*76 + s)*64)*128;
    for (int i=t; i<8192; i+=256) sm[i]      = Fg[base+i];
    for (int i=t; i<8192; i+=256) sm[8192+i] = Gg[base+i];
    __syncthreads();

    int k = t & 127, ch = t >> 7;
    float sc[64];
    #pragma unroll
    for (int j=0;j<64;++j) sc[j]=0.f;
    for (int d=0; d<64; ++d){
        float gk = sm[8192 + d*128 + k];
        #pragma unroll
        for (int cj=0; cj<16; ++cj){
            float4 f4 = *(const float4*)&sm[d*128 + ch*64 + cj*4];
            sc[cj*4+0] += f4.x*gk; sc[cj*4+1] += f4.y*gk;
            sc[cj*4+2] += f4.z*gk; sc[cj*4+3] += f4.w*gk;
        }
    }
    __syncthreads();                       // F,G now dead
    float m = -1e30f;
    #pragma unroll
    for (int j=0;j<64;++j) m = fmaxf(m, sc[j]);
    sm[t] = m;                              // red region sm[0..256)
    for (int i=t; i<8192; i+=256) sm[8192+i] = Vg[base+i];  // V into dead G
    __syncthreads();
    m = fmaxf(sm[k], sm[128+k]);
    float lsum = 0.f;
    #pragma unroll
    for (int j=0;j<64;++j){ sc[j] = __expf(sc[j]-m); lsum += sc[j]; }
    __syncthreads();
    sm[t] = lsum;
    __syncthreads();
    float rinv = 1.f/(sm[k] + sm[128+k]);
    #pragma unroll
    for (int j=0;j<64;++j) sc[j] *= rinv;
    __syncthreads();                        // red reads done

    if (ch == 0){                           // beta half 0 (c in [0,64))
        #pragma unroll
        for (int j=0;j<64;++j) sm[j*128 + k] = sc[j];
    }
    __syncthreads();

    int k2 = t & 31, dq = t >> 5;           // dq 0..7
    float ao[8][4];
    #pragma unroll
    for (int j=0;j<8;++j)
        #pragma unroll
        for (int mm=0;mm<4;++mm) ao[j][mm]=0.f;

    for (int c2=0; c2<64; ++c2){
        float bv0 = sm[c2*128 + k2],    bv1 = sm[c2*128 + k2+32];
        float bv2 = sm[c2*128 + k2+64], bv3 = sm[c2*128 + k2+96];
        #pragma unroll
        for (int j=0;j<8;++j){
            float v = sm[8192 + (dq*8+j)*128 + c2];
            ao[j][0]+=v*bv0; ao[j][1]+=v*bv1; ao[j][2]+=v*bv2; ao[j][3]+=v*bv3;
        }
    }
    __syncthreads();
    if (ch == 1){                           // beta half 1 (c in [64,128))
        #pragma unroll
        for (int j=0;j<64;++j) sm[j*128 + k] = sc[j];
    }
    __syncthreads();
    for (int c2=64; c2<128; ++c2){
        float bv0 = sm[(c2-64)*128 + k2],    bv1 = sm[(c2-64)*128 + k2+32];
        float bv2 = sm[(c2-64)*128 + k2+64], bv3 = sm[(c2-64)*128 + k2+96];
        #pragma unroll
        for (int j=0;j<8;++j){
            float v = sm[8192 + (dq*8+j)*128 + c2];
            ao[j][0]+=v*bv0; ao[j][1]+=v*bv1; ao[j][2]+=v*bv2; ao[j][3]+=v*bv3;
        }
    }

    float gm = gamma[0];
    size_t sbase = (size_t)(s*32 + b_base + bl)*8192;   // global (s,b) row
    #pragma unroll
    for (int j=0;j<8;++j){
        int d = dq*8+j;
        #pragma unroll
        for (int mm=0;mm<4;++mm){
            int kk = k2 + 32*mm;
            float val = gm*ao[j][mm] + V1g[base + (size_t)d*128 + kk];
            seq_bf[sbase + (size_t)d*128 + kk] = f2bf(val);
        }
    }
}

// ---------------- wih -> bf16 ----------------------------------------------
__global__ __launch_bounds__(256) void conv_wih_bf16(const float* __restrict__ w,
        unsigned short* __restrict__ o)
{
    int i = (blockIdx.x*256 + threadIdx.x)*4;   // < 1536*8192
    float4 v = *(const float4*)&w[i];
    ushort4 r;
    r.x = f2bf(v.x); r.y = f2bf(v.y); r.z = f2bf(v.z); r.w = f2bf(v.w);
    *(ushort4*)&o[i] = r;
}

// ---------------- big GEMM (bf16 MFMA): xg = seq_bf . wih_bf^T + bih -------
// grid (12, 19): n-tile, m-tile of 128x128 ; BK=64 ; 4 waves, 4x4 frags/wave
__global__ __launch_bounds__(256) void gemm_xg_mfma(const unsigned short* __restrict__ A,
        const unsigned short* __restrict__ Bw, const float* __restrict__ bih,
        float* __restrict__ out)
{
    __shared__ float AsF[128*36];   // 128 rows x (64+8 pad) bf16 = 36 floats
    __shared__ float BsF[128*36];
    int t = threadIdx.x;
    int n0 = blockIdx.x*128, m0 = blockIdx.y*128;
    int l = t & 63, w = t >> 6;
    int wm = w >> 1, wn = w & 1;
    int rr = t >> 3, cs = t & 7;     // staging: row-part, col-seg
    int lr = l & 15, lh = l >> 4;    // fragment lane decomposition

    f32x4 acc[4][4];
    #pragma unroll
    for (int mi=0;mi<4;++mi)
        #pragma unroll
        for (int ni=0;ni<4;++ni) acc[mi][ni] = (f32x4)0.f;

    float4 ra[4], rb[4];
    #pragma unroll
    for (int i=0;i<4;++i){
        ra[i] = *(const float4*)(A  + (size_t)(m0 + rr + 32*i)*8192 + cs*8);
        rb[i] = *(const float4*)(Bw + (size_t)(n0 + rr + 32*i)*8192 + cs*8);
    }
    for (int kt=0; kt<128; ++kt){
        __syncthreads();
        #pragma unroll
        for (int i=0;i<4;++i){
            *(float4*)&AsF[(rr+32*i)*36 + cs*4] = ra[i];
            *(float4*)&BsF[(rr+32*i)*36 + cs*4] = rb[i];
        }
        __syncthreads();
        if (kt < 127){
            int k0 = (kt+1)*64;
            #pragma unroll
            for (int i=0;i<4;++i){
                ra[i] = *(const float4*)(A  + (size_t)(m0 + rr + 32*i)*8192 + k0 + cs*8);
                rb[i] = *(const float4*)(Bw + (size_t)(n0 + rr + 32*i)*8192 + k0 + cs*8);
            }
        }
        #pragma unroll
        for (int kk=0;kk<2;++kk){
            short8 af[4], bf[4];
            #pragma unroll
            for (int mi=0;mi<4;++mi)
                af[mi] = *(short8*)&AsF[(wm*64 + mi*16 + lr)*36 + kk*16 + lh*4];
            #pragma unroll
            for (int ni=0;ni<4;++ni)
                bf[ni] = *(short8*)&BsF[(wn*64 + ni*16 + lr)*36 + kk*16 + lh*4];
            #pragma unroll
            for (int mi=0;mi<4;++mi)
                #pragma unroll
                for (int ni=0;ni<4;++ni)
                    acc[mi][ni] = __builtin_amdgcn_mfma_f32_16x16x32_bf16(
                                      af[mi], bf[ni], acc[mi][ni], 0, 0, 0);
        }
    }
    #pragma unroll
    for (int ni=0;ni<4;++ni){
        int n = n0 + wn*64 + ni*16 + lr;
        float bv = bih[n];
        #pragma unroll
        for (int mi=0;mi<4;++mi){
            #pragma unroll
            for (int q=0;q<4;++q){
                int m = m0 + wm*64 + mi*16 + lh*4 + q;
                out[(size_t)m*1536 + n] = acc[mi][ni][q] + bv;
            }
        }
    }
}

// ---------------- GRU weight repack ----------------------------------------
__global__ __launch_bounds__(256) void build_whhp_k(const float* __restrict__ whh,
        float4* __restrict__ whh_p)
{
    int idx = blockIdx.x*256 + threadIdx.x;   // < 512*512
    int i = idx >> 9, j = idx & 511;
    float4 o;
    o.x = whh[(size_t)j*512 + i];
    o.y = whh[(size_t)(512+j)*512 + i];
    o.z = whh[(size_t)(1024+j)*512 + i];
    o.w = 0.f;
    whh_p[idx] = o;
}

// ---------------- one GRU step ---------------------------------------------
__global__ __launch_bounds__(256) void gru_step_k(const float4* __restrict__ whh_p,
        const float* __restrict__ xg, const float* __restrict__ bhh,
        float* __restrict__ outs, int s)
{
    __shared__ float hl[2048];
    int t = threadIdx.x;
    int jc = blockIdx.x & 7, bq = blockIdx.x >> 3;
    for (int idx=t; idx<2048; idx+=256)
        hl[idx] = outs[(size_t)s*16384 + (size_t)(bq*4 + (idx>>9))*512 + (idx&511)];
    __syncthreads();
    int j = jc*64 + (t & 63), bl_ = t >> 6, b = bq*4 + bl_;
    float a0=0.f,a1=0.f,a2=0.f;
    const float4* wp = whh_p + j;
    const float* hb = hl + bl_*512;
    #pragma unroll 4
    for (int i=0;i<512;++i){
        float4 w4 = wp[(size_t)i*512];
        float hv = hb[i];
        a0 += w4.x*hv; a1 += w4.y*hv; a2 += w4.z*hv;
    }
    size_t xi = (size_t)(s*32 + b)*1536 + j;
    float xr = xg[xi], xz = xg[xi+512], xn = xg[xi+1024];
    float hr = a0 + bhh[j], hz = a1 + bhh[512+j], hn = a2 + bhh[1024+j];
    float r = sigm(xr+hr), z = sigm(xz+hz);
    float n = tanhf(xn + r*hn);
    float hp = hb[j];
    float hnew = (1.f - z)*n + z*hp;
    outs[(size_t)(s+1)*16384 + (size_t)b*512 + j] = hnew;
}

// ---------------- final attention pooling over s ---------------------------
__global__ __launch_bounds__(256) void pool_k(const float* __restrict__ outs,
        const float* __restrict__ fcw, const float* __restrict__ fcb,
        float* __restrict__ out)
{
    __shared__ float att[80], watt[128];
    int b = blockIdx.x, t = threadIdx.x;
    int w = t >> 6, lane = t & 63;
    for (int s = w; s < 76; s += 4){
        float acc = 0.f;
        const float* op = outs + (size_t)(s+1)*16384 + (size_t)b*512;
        #pragma unroll
        for (int hh = 0; hh < 512; hh += 64) acc += op[hh+lane]*fcw[hh+lane];
        #pragma unroll
        for (int off=32; off; off>>=1) acc += __shfl_down(acc, off);
        if (lane==0) att[s] = acc + fcb[0];
    }
    __syncthreads();
    if (t < 64){
        float a0 = (t<76)? att[t] : -1e30f;
        float a1 = (t+64<76)? att[t+64] : -1e30f;
        float m = fmaxf(a0,a1);
        #pragma unroll
        for (int off=32; off; off>>=1) m = fmaxf(m, __shfl_xor(m, off));
        float e0 = (t<76)? __expf(a0-m) : 0.f;
        float e1 = (t+64<76)? __expf(a1-m) : 0.f;
        float ssum = e0+e1;
        #pragma unroll
        for (int off=32; off; off>>=1) ssum += __shfl_xor(ssum, off);
        float ri = 1.f/ssum;
        watt[t] = e0*ri;
        watt[t+64] = e1*ri;
    }
    __syncthreads();
    for (int h = t; h < 512; h += 256){
        float acc=0.f;
        for (int s=0;s<76;++s) acc += watt[s]*outs[(size_t)(s+1)*16384 + (size_t)b*512 + h];
        out[(size_t)b*512 + h] = acc;
    }
}

// ---------------- launch ----------------------------------------------------
extern "C" void kernel_launch(void* const* d_in, const int* in_sizes, int n_in,
                              void* d_out, int out_size, void* d_ws, size_t ws_size,
                              hipStream_t stream)
{
    const float* x   = (const float*)d_in[0];
    const float* w1  = (const float*)d_in[1];  const float* b1  = (const float*)d_in[2];
    const float* w2  = (const float*)d_in[3];  const float* b2  = (const float*)d_in[4];
    const float* w3  = (const float*)d_in[5];  const float* b3  = (const float*)d_in[6];
    const float* w4  = (const float*)d_in[7];  const float* b4  = (const float*)d_in[8];
    const float* wq  = (const float*)d_in[9];  const float* wk  = (const float*)d_in[10];
    const float* wv  = (const float*)d_in[11]; const float* wv1 = (const float*)d_in[12];
    const float* gamma = (const float*)d_in[13];
    const float* wih = (const float*)d_in[14]; const float* whh = (const float*)d_in[15];
    const float* bih = (const float*)d_in[16]; const float* bhh = (const float*)d_in[17];
    const float* fcw = (const float*)d_in[18]; const float* fcb = (const float*)d_in[19];

    // workspace layout (float-equivalents); total 27,656,192 fl = 105.5 MiB
    float* ws = (float*)d_ws;
    size_t off = 0;
    float* bufA = ws + off; off += 3932160ull;    // 2*64*240*128
    float* bufB = ws + off; off += 3866624ull;    // 2*64*236*128 (also F|G)
    float* bufC = ws + off; off += 3801088ull;    // 2*64*232*128 (also V|V1)
    unsigned short* seq_bf = (unsigned short*)(ws + off); off += 9961472ull; // 2432*8192 bf16
    float* xg   = ws + off; off += 3735552ull;    // 2432*1536
    float* outs = ws + off; off += 77ull*16384;   // (76+1)*32*512
    float* wrep = ws + off; off += 49152ull;      // 192*256
    float4* whh_p = (float4*)(ws + off); off += 4ull*262144; // 512*512 float4
    // wih_bf overlays bufA+bufB after the conv/attend loop (6,291,456 fl-eq needed, 7,798,784 avail)
    unsigned short* wih_bf = (unsigned short*)bufA;

    repack_w_k<<<192, 256, 0, stream>>>(wq, wk, wv, wv1, wrep);
    build_whhp_k<<<1024, 256, 0, stream>>>(whh, whh_p);
    hipMemsetAsync(outs, 0, 16384*sizeof(float), stream);

    float* Fb  = bufB;
    float* Gb  = bufB + 1245184ull;   // 2*76*64*128
    float* Vb  = bufC;
    float* V1b = bufC + 1245184ull;

    for (int chunk=0; chunk<16; ++chunk){
        int b_base = chunk*2;
        conv1_k<<<15360, 256, 0, stream>>>(x, bufA, w1, b1, b_base);
        conv_k<<<dim3(118,4,2), 256, 0, stream>>>(bufA, bufB, w2, b2, 240, 236);
        conv_k<<<dim3(116,4,2), 256, 0, stream>>>(bufB, bufC, w3, b3, 236, 232);
        conv_k<<<dim3(114,4,2), 256, 0, stream>>>(bufC, bufA, w4, b4, 232, 228);
        project_k<<<dim3(76,2), 1024, 0, stream>>>(bufA, wrep, Fb, Gb, Vb, V1b);
        attend_k<<<dim3(76,2), 256, 0, stream>>>(Fb, Gb, Vb, V1b, gamma, seq_bf, b_base);
    }
    conv_wih_bf16<<<12288, 256, 0, stream>>>(wih, wih_bf);
    gemm_xg_mfma<<<dim3(12,19), 256, 0, stream>>>(seq_bf, wih_bf, bih, xg);
    for (int s=0; s<76; ++s)
        gru_step_k<<<64, 256, 0, stream>>>(whh_p, xg, bhh, outs, s);
    pool_k<<<32, 256, 0, stream>>>(outs, fcw, fcb, (float*)d_out);
}

// Round 7
// 3685.524 us; speedup vs baseline: 2.6583x; 2.1107x over previous
//
#include <hip/hip_runtime.h>
#include <math.h>

// ---------------- problem constants ----------------
// B=32 (16 chunks of 2), L=244, C=128, F=64, KS=5
// conv lengths: 244 -> 240 -> 236 -> 232 -> 228 ; S=76 ; F3=192 ; D_SA=64
// HID=512, 3*HID=1536 ; big GEMM: M=2432, K=8192, N=1536
// R7 = R6 with ONE fix: conv1_k weight staging covered all 320 entries
// (was `if (t<320)` with 256 threads -> w1s[256..319] uninitialized garbage).
// Workspace ~100.6 MB.

typedef __attribute__((ext_vector_type(8))) short short8;
typedef __attribute__((ext_vector_type(4))) float f32x4;

__device__ inline float sigm(float x){ return 1.f/(1.f+__expf(-x)); }
__device__ inline unsigned short f2bf(float f){
    unsigned int u = __float_as_uint(f);
    u = (u + 0x7FFFu + ((u >> 16) & 1u)) >> 16;
    return (unsigned short)u;
}
__device__ inline float bf2f(unsigned short h){
    return __uint_as_float(((unsigned int)h) << 16);
}

// ---------------- conv1: x[b][l][c] fp32 -> h1 pair [b][l][c][f] -----------
__global__ __launch_bounds__(256) void conv1_k(const float* __restrict__ x,
        unsigned short* __restrict__ out_h, unsigned short* __restrict__ out_l,
        const float* __restrict__ w1, const float* __restrict__ b1, int b_base)
{
    __shared__ float w1s[320];
    __shared__ float b1s[64];
    int t = threadIdx.x;
    for (int idx = t; idx < 320; idx += 256) w1s[idx] = w1[idx];   // FIX: cover all 320
    if (t < 64)  b1s[t] = b1[t];
    __syncthreads();
    int i = blockIdx.x*256 + t;          // < 2*240*128
    int c = i & 127; int t2 = i >> 7;
    int l = t2 % 240; int b = t2 / 240;
    const float* xp = x + ((size_t)(b_base + b)*244 + l)*128 + c;
    float xv[5];
    #pragma unroll
    for (int k=0;k<5;++k) xv[k] = xp[k*128];
    unsigned short* oh = out_h + (size_t)i*64;
    unsigned short* ol = out_l + (size_t)i*64;
    #pragma unroll
    for (int f8=0; f8<8; ++f8){
        unsigned short rh[8], rl[8];
        #pragma unroll
        for (int j=0;j<8;++j){
            int f = f8*8 + j;
            float a = b1s[f];
            #pragma unroll
            for (int k=0;k<5;++k) a += w1s[f*5+k]*xv[k];
            a = a > 0.f ? a : 0.f;
            unsigned short hi = f2bf(a);
            rh[j] = hi;
            rl[j] = f2bf(a - bf2f(hi));
        }
        *(short8*)(oh + f8*8) = *(short8*)rh;
        *(short8*)(ol + f8*8) = *(short8*)rl;
    }
}

// ---------------- conv weight repack pairs: [layer][k][fo][fi] -------------
__global__ __launch_bounds__(256) void repack_convw_k(const float* __restrict__ w2,
        const float* __restrict__ w3, const float* __restrict__ w4,
        unsigned short* __restrict__ wbf_h, unsigned short* __restrict__ wbf_l)
{
    int idx = blockIdx.x*256 + threadIdx.x;   // < 61440
    int fi = idx & 63; int t2 = idx >> 6;
    int fo = t2 & 63;  int t3 = t2 >> 6;
    int k = t3 % 5;    int layer = t3 / 5;
    const float* ws_ = (layer==0)? w2 : (layer==1)? w3 : w4;
    float v = ws_[(fo*64 + fi)*5 + k];
    unsigned short hi = f2bf(v);
    wbf_h[idx] = hi;
    wbf_l[idx] = f2bf(v - bf2f(hi));
}

// ---------------- conv2/3/4 split MFMA: pairs -> pairs, relu ---------------
// block: one (b,l): M=128(c) x N=64(fo), K=5x64 ; 3-term split product
__global__ __launch_bounds__(256) void conv_mfma_s(
        const unsigned short* __restrict__ in_h, const unsigned short* __restrict__ in_l,
        unsigned short* __restrict__ out_h, unsigned short* __restrict__ out_l,
        const unsigned short* __restrict__ wk_h, const unsigned short* __restrict__ wk_l,
        const float* __restrict__ bias, int Lin, int Lout)
{
    __shared__ __align__(16) unsigned short Abh[128*72], Abl[128*72];
    __shared__ __align__(16) unsigned short Wbh[64*72],  Wbl[64*72];
    int t = threadIdx.x;
    int l = blockIdx.x, b = blockIdx.y;
    int lane = t & 63, w = t >> 6;
    int lr = lane & 15, lh = lane >> 4;
    f32x4 acc[2][4];
    #pragma unroll
    for (int mf=0;mf<2;++mf)
        #pragma unroll
        for (int nf=0;nf<4;++nf) acc[mf][nf] = (f32x4)0.f;

    const size_t ib = ((size_t)b*Lin + l)*8192;
    for (int k=0;k<5;++k){
        __syncthreads();
        #pragma unroll
        for (int i=0;i<4;++i){
            int idx = i*256 + t; int row = idx>>3, c8 = idx&7;
            *(short8*)&Abh[row*72 + c8*8] = *(const short8*)(in_h + ib + (size_t)k*8192 + idx*8);
            *(short8*)&Abl[row*72 + c8*8] = *(const short8*)(in_l + ib + (size_t)k*8192 + idx*8);
        }
        #pragma unroll
        for (int i=0;i<2;++i){
            int idx = i*256 + t; int row = idx>>3, c8 = idx&7;
            *(short8*)&Wbh[row*72 + c8*8] = *(const short8*)(wk_h + k*4096 + idx*8);
            *(short8*)&Wbl[row*72 + c8*8] = *(const short8*)(wk_l + k*4096 + idx*8);
        }
        __syncthreads();
        #pragma unroll
        for (int kk=0;kk<2;++kk){
            short8 ah[2], al[2], bh[4], blo[4];
            #pragma unroll
            for (int mf=0;mf<2;++mf){
                ah[mf] = *(const short8*)&Abh[(w*32+mf*16+lr)*72 + kk*32 + lh*8];
                al[mf] = *(const short8*)&Abl[(w*32+mf*16+lr)*72 + kk*32 + lh*8];
            }
            #pragma unroll
            for (int nf=0;nf<4;++nf){
                bh[nf]  = *(const short8*)&Wbh[(nf*16+lr)*72 + kk*32 + lh*8];
                blo[nf] = *(const short8*)&Wbl[(nf*16+lr)*72 + kk*32 + lh*8];
            }
            #pragma unroll
            for (int mf=0;mf<2;++mf)
                #pragma unroll
                for (int nf=0;nf<4;++nf){
                    acc[mf][nf] = __builtin_amdgcn_mfma_f32_16x16x32_bf16(ah[mf], bh[nf],  acc[mf][nf], 0,0,0);
                    acc[mf][nf] = __builtin_amdgcn_mfma_f32_16x16x32_bf16(ah[mf], blo[nf], acc[mf][nf], 0,0,0);
                    acc[mf][nf] = __builtin_amdgcn_mfma_f32_16x16x32_bf16(al[mf], bh[nf],  acc[mf][nf], 0,0,0);
                }
        }
    }
    const size_t ob = ((size_t)b*Lout + l)*8192;
    #pragma unroll
    for (int nf=0;nf<4;++nf){
        int fo = nf*16 + lr;
        float bv = bias[fo];
        #pragma unroll
        for (int mf=0;mf<2;++mf)
            #pragma unroll
            for (int q=0;q<4;++q){
                int c = w*32 + mf*16 + lh*4 + q;
                float v = acc[mf][nf][q] + bv;
                v = v > 0.f ? v : 0.f;
                unsigned short hi = f2bf(v);
                out_h[ob + c*64 + fo] = hi;
                out_l[ob + c*64 + fo] = f2bf(v - bf2f(hi));
            }
    }
}

// ---------------- attention weight repack pairs: [md][jj*64+f] -------------
__global__ __launch_bounds__(256) void repack_wrep_k(const float* __restrict__ wq,
        const float* __restrict__ wk, const float* __restrict__ wv,
        const float* __restrict__ wv1,
        unsigned short* __restrict__ wr_h, unsigned short* __restrict__ wr_l)
{
    int idx = blockIdx.x*256 + threadIdx.x;   // < 256*192
    int ko = idx % 192; int md = idx / 192;
    int m = md >> 6, d = md & 63;
    int jj = ko >> 6, f = ko & 63;
    const float* src = (m==0)? wq : (m==1)? wk : (m==2)? wv : wv1;
    float v = src[d*192 + f*3 + jj];
    unsigned short hi = f2bf(v);
    wr_h[idx] = hi;
    wr_l[idx] = f2bf(v - bf2f(hi));
}

// ---------------- projection split MFMA: per (b,s,mz) ----------------------
// M=128(c) x N=64(d) x K=192 ; mz in {F,G,V,V1} ; output fp32 [bs][d][c]
__global__ __launch_bounds__(256) void project_mfma_s(
        const unsigned short* __restrict__ h_h, const unsigned short* __restrict__ h_l,
        const unsigned short* __restrict__ wr_h, const unsigned short* __restrict__ wr_l,
        float* __restrict__ Fo, float* __restrict__ Go,
        float* __restrict__ Vo, float* __restrict__ V1o)
{
    __shared__ __align__(16) unsigned short Abh[128*72], Abl[128*72];
    __shared__ __align__(16) unsigned short Bbh[64*72],  Bbl[64*72];
    int t = threadIdx.x;
    int s = blockIdx.x, bl = blockIdx.y, mz = blockIdx.z;
    int lane = t & 63, w = t >> 6;
    int wm = w >> 1, wn = w & 1;
    int lr = lane & 15, lh = lane >> 4;
    f32x4 acc[4][2];
    #pragma unroll
    for (int mf=0;mf<4;++mf)
        #pragma unroll
        for (int nf=0;nf<2;++nf) acc[mf][nf] = (f32x4)0.f;

    for (int jj=0;jj<3;++jj){
        __syncthreads();
        const size_t ao_ = ((size_t)bl*228 + 3*s + jj)*8192;
        #pragma unroll
        for (int i=0;i<4;++i){
            int idx = i*256 + t; int row = idx>>3, c8 = idx&7;
            *(short8*)&Abh[row*72 + c8*8] = *(const short8*)(h_h + ao_ + idx*8);
            *(short8*)&Abl[row*72 + c8*8] = *(const short8*)(h_l + ao_ + idx*8);
        }
        #pragma unroll
        for (int i=0;i<2;++i){
            int idx = i*256 + t; int row = idx>>3, c8 = idx&7;
            size_t wo = (size_t)(mz*64 + row)*192 + jj*64 + c8*8;
            *(short8*)&Bbh[row*72 + c8*8] = *(const short8*)(wr_h + wo);
            *(short8*)&Bbl[row*72 + c8*8] = *(const short8*)(wr_l + wo);
        }
        __syncthreads();
        #pragma unroll
        for (int kk=0;kk<2;++kk){
            short8 ah[4], al[4], bh[2], blo[2];
            #pragma unroll
            for (int mf=0;mf<4;++mf){
                ah[mf] = *(const short8*)&Abh[(wm*64+mf*16+lr)*72 + kk*32 + lh*8];
                al[mf] = *(const short8*)&Abl[(wm*64+mf*16+lr)*72 + kk*32 + lh*8];
            }
            #pragma unroll
            for (int nf=0;nf<2;++nf){
                bh[nf]  = *(const short8*)&Bbh[(wn*32+nf*16+lr)*72 + kk*32 + lh*8];
                blo[nf] = *(const short8*)&Bbl[(wn*32+nf*16+lr)*72 + kk*32 + lh*8];
            }
            #pragma unroll
            for (int mf=0;mf<4;++mf)
                #pragma unroll
                for (int nf=0;nf<2;++nf){
                    acc[mf][nf] = __builtin_amdgcn_mfma_f32_16x16x32_bf16(ah[mf], bh[nf],  acc[mf][nf], 0,0,0);
                    acc[mf][nf] = __builtin_amdgcn_mfma_f32_16x16x32_bf16(ah[mf], blo[nf], acc[mf][nf], 0,0,0);
                    acc[mf][nf] = __builtin_amdgcn_mfma_f32_16x16x32_bf16(al[mf], bh[nf],  acc[mf][nf], 0,0,0);
                }
        }
    }
    float* dst = (mz==0)? Fo : (mz==1)? Go : (mz==2)? Vo : V1o;
    size_t bs = (size_t)bl*76 + s;
    #pragma unroll
    for (int mf=0;mf<4;++mf)
        #pragma unroll
        for (int nf=0;nf<2;++nf){
            int d = wn*32 + nf*16 + lr;
            int c0 = wm*64 + mf*16 + lh*4;
            *(f32x4*)&dst[(bs*64 + d)*128 + c0] = acc[mf][nf];
        }
}

// ---------------- attention, fp32, 64KB LDS (R3-PROVEN, unpermuted) --------
__global__ __launch_bounds__(256) void attend_k(const float* __restrict__ Fg,
        const float* __restrict__ Gg, const float* __restrict__ Vg,
        const float* __restrict__ V1g, const float* __restrict__ gamma,
        unsigned short* __restrict__ seq_bf, int b_base)
{
    __shared__ float sm[16384];    // exactly 64 KB
    int t = threadIdx.x;
    int s = blockIdx.x, bl = blockIdx.y;
    size_t base = ((size_t)bl*76 + s)*8192;
    for (int i=t; i<8192; i+=256) sm[i]      = Fg[base+i];
    for (int i=t; i<8192; i+=256) sm[8192+i] = Gg[base+i];
    __syncthreads();

    int k = t & 127, ch = t >> 7;
    float sc[64];
    #pragma unroll
    for (int j=0;j<64;++j) sc[j]=0.f;
    for (int d=0; d<64; ++d){
        float gk = sm[8192 + d*128 + k];
        #pragma unroll
        for (int cj=0; cj<16; ++cj){
            float4 f4 = *(const float4*)&sm[d*128 + ch*64 + cj*4];
            sc[cj*4+0] += f4.x*gk; sc[cj*4+1] += f4.y*gk;
            sc[cj*4+2] += f4.z*gk; sc[cj*4+3] += f4.w*gk;
        }
    }
    __syncthreads();                       // F,G now dead
    float m = -1e30f;
    #pragma unroll
    for (int j=0;j<64;++j) m = fmaxf(m, sc[j]);
    sm[t] = m;                              // red region sm[0..256)
    for (int i=t; i<8192; i+=256) sm[8192+i] = Vg[base+i];  // V into dead G
    __syncthreads();
    m = fmaxf(sm[k], sm[128+k]);
    float lsum = 0.f;
    #pragma unroll
    for (int j=0;j<64;++j){ sc[j] = __expf(sc[j]-m); lsum += sc[j]; }
    __syncthreads();
    sm[t] = lsum;
    __syncthreads();
    float rinv = 1.f/(sm[k] + sm[128+k]);
    #pragma unroll
    for (int j=0;j<64;++j) sc[j] *= rinv;
    __syncthreads();                        // red reads done

    if (ch == 0){                           // beta half 0 (c in [0,64))
        #pragma unroll
        for (int j=0;j<64;++j) sm[j*128 + k] = sc[j];
    }
    __syncthreads();

    int k2 = t & 31, dq = t >> 5;           // dq 0..7
    float ao[8][4];
    #pragma unroll
    for (int j=0;j<8;++j)
        #pragma unroll
        for (int mm=0;mm<4;++mm) ao[j][mm]=0.f;

    for (int c2=0; c2<64; ++c2){
        float bv0 = sm[c2*128 + k2],    bv1 = sm[c2*128 + k2+32];
        float bv2 = sm[c2*128 + k2+64], bv3 = sm[c2*128 + k2+96];
        #pragma unroll
        for (int j=0;j<8;++j){
            float v = sm[8192 + (dq*8+j)*128 + c2];
            ao[j][0]+=v*bv0; ao[j][1]+=v*bv1; ao[j][2]+=v*bv2; ao[j][3]+=v*bv3;
        }
    }
    __syncthreads();
    if (ch == 1){                           // beta half 1 (c in [64,128))
        #pragma unroll
        for (int j=0;j<64;++j) sm[j*128 + k] = sc[j];
    }
    __syncthreads();
    for (int c2=64; c2<128; ++c2){
        float bv0 = sm[(c2-64)*128 + k2],    bv1 = sm[(c2-64)*128 + k2+32];
        float bv2 = sm[(c2-64)*128 + k2+64], bv3 = sm[(c2-64)*128 + k2+96];
        #pragma unroll
        for (int j=0;j<8;++j){
            float v = sm[8192 + (dq*8+j)*128 + c2];
            ao[j][0]+=v*bv0; ao[j][1]+=v*bv1; ao[j][2]+=v*bv2; ao[j][3]+=v*bv3;
        }
    }

    float gm = gamma[0];
    size_t sbase = (size_t)(s*32 + b_base + bl)*8192;   // global (s,b) row
    #pragma unroll
    for (int j=0;j<8;++j){
        int d = dq*8+j;
        #pragma unroll
        for (int mm=0;mm<4;++mm){
            int kk = k2 + 32*mm;
            float val = gm*ao[j][mm] + V1g[base + (size_t)d*128 + kk];
            seq_bf[sbase + (size_t)d*128 + kk] = f2bf(val);
        }
    }
}

// ---------------- wih -> bf16 (IDENTITY, R3-proven) ------------------------
__global__ __launch_bounds__(256) void conv_wih_bf16(const float* __restrict__ w,
        unsigned short* __restrict__ o)
{
    int i = (blockIdx.x*256 + threadIdx.x)*4;   // < 1536*8192
    float4 v = *(const float4*)&w[i];
    ushort4 r;
    r.x = f2bf(v.x); r.y = f2bf(v.y); r.z = f2bf(v.z); r.w = f2bf(v.w);
    *(ushort4*)&o[i] = r;
}

// ---------------- big GEMM bf16 MFMA (R3-proven) ---------------------------
__global__ __launch_bounds__(256) void gemm_xg_mfma(const unsigned short* __restrict__ A,
        const unsigned short* __restrict__ Bw, const float* __restrict__ bih,
        float* __restrict__ out)
{
    __shared__ float AsF[128*36];
    __shared__ float BsF[128*36];
    int t = threadIdx.x;
    int n0 = blockIdx.x*128, m0 = blockIdx.y*128;
    int l = t & 63, w = t >> 6;
    int wm = w >> 1, wn = w & 1;
    int rr = t >> 3, cs = t & 7;
    int lr = l & 15, lh = l >> 4;
    f32x4 acc[4][4];
    #pragma unroll
    for (int mi=0;mi<4;++mi)
        #pragma unroll
        for (int ni=0;ni<4;++ni) acc[mi][ni] = (f32x4)0.f;

    float4 ra[4], rb[4];
    #pragma unroll
    for (int i=0;i<4;++i){
        ra[i] = *(const float4*)(A  + (size_t)(m0 + rr + 32*i)*8192 + cs*8);
        rb[i] = *(const float4*)(Bw + (size_t)(n0 + rr + 32*i)*8192 + cs*8);
    }
    for (int kt=0; kt<128; ++kt){
        __syncthreads();
        #pragma unroll
        for (int i=0;i<4;++i){
            *(float4*)&AsF[(rr+32*i)*36 + cs*4] = ra[i];
            *(float4*)&BsF[(rr+32*i)*36 + cs*4] = rb[i];
        }
        __syncthreads();
        if (kt < 127){
            int k0 = (kt+1)*64;
            #pragma unroll
            for (int i=0;i<4;++i){
                ra[i] = *(const float4*)(A  + (size_t)(m0 + rr + 32*i)*8192 + k0 + cs*8);
                rb[i] = *(const float4*)(Bw + (size_t)(n0 + rr + 32*i)*8192 + k0 + cs*8);
            }
        }
        #pragma unroll
        for (int kk=0;kk<2;++kk){
            short8 af[4], bf_[4];
            #pragma unroll
            for (int mi=0;mi<4;++mi)
                af[mi] = *(short8*)&AsF[(wm*64 + mi*16 + lr)*36 + kk*16 + lh*4];
            #pragma unroll
            for (int ni=0;ni<4;++ni)
                bf_[ni] = *(short8*)&BsF[(wn*64 + ni*16 + lr)*36 + kk*16 + lh*4];
            #pragma unroll
            for (int mi=0;mi<4;++mi)
                #pragma unroll
                for (int ni=0;ni<4;++ni)
                    acc[mi][ni] = __builtin_amdgcn_mfma_f32_16x16x32_bf16(
                                      af[mi], bf_[ni], acc[mi][ni], 0, 0, 0);
        }
    }
    #pragma unroll
    for (int ni=0;ni<4;++ni){
        int n = n0 + wn*64 + ni*16 + lr;
        float bv = bih[n];
        #pragma unroll
        for (int mi=0;mi<4;++mi){
            #pragma unroll
            for (int q=0;q<4;++q){
                int m = m0 + wm*64 + mi*16 + lh*4 + q;
                out[(size_t)m*1536 + n] = acc[mi][ni][q] + bv;
            }
        }
    }
}

// ---------------- GRU weight repack ----------------------------------------
__global__ __launch_bounds__(256) void build_whhp_k(const float* __restrict__ whh,
        float4* __restrict__ whh_p)
{
    int idx = blockIdx.x*256 + threadIdx.x;   // < 512*512
    int i = idx >> 9, j = idx & 511;
    float4 o;
    o.x = whh[(size_t)j*512 + i];
    o.y = whh[(size_t)(512+j)*512 + i];
    o.z = whh[(size_t)(1024+j)*512 + i];
    o.w = 0.f;
    whh_p[idx] = o;
}

// ---------------- one GRU step (R3-proven) ---------------------------------
__global__ __launch_bounds__(256) void gru_step_k(const float4* __restrict__ whh_p,
        const float* __restrict__ xg, const float* __restrict__ bhh,
        float* __restrict__ outs, int s)
{
    __shared__ float hl[2048];
    int t = threadIdx.x;
    int jc = blockIdx.x & 7, bq = blockIdx.x >> 3;
    for (int idx=t; idx<2048; idx+=256)
        hl[idx] = outs[(size_t)s*16384 + (size_t)(bq*4 + (idx>>9))*512 + (idx&511)];
    __syncthreads();
    int j = jc*64 + (t & 63), bl_ = t >> 6, b = bq*4 + bl_;
    float a0=0.f,a1=0.f,a2=0.f;
    const float4* wp = whh_p + j;
    const float* hb = hl + bl_*512;
    #pragma unroll 4
    for (int i=0;i<512;++i){
        float4 w4 = wp[(size_t)i*512];
        float hv = hb[i];
        a0 += w4.x*hv; a1 += w4.y*hv; a2 += w4.z*hv;
    }
    size_t xi = (size_t)(s*32 + b)*1536 + j;
    float xr = xg[xi], xz = xg[xi+512], xn = xg[xi+1024];
    float hr = a0 + bhh[j], hz = a1 + bhh[512+j], hn = a2 + bhh[1024+j];
    float r = sigm(xr+hr), z = sigm(xz+hz);
    float n = tanhf(xn + r*hn);
    float hp = hb[j];
    float hnew = (1.f - z)*n + z*hp;
    outs[(size_t)(s+1)*16384 + (size_t)b*512 + j] = hnew;
}

// ---------------- final attention pooling over s ---------------------------
__global__ __launch_bounds__(256) void pool_k(const float* __restrict__ outs,
        const float* __restrict__ fcw, const float* __restrict__ fcb,
        float* __restrict__ out)
{
    __shared__ float att[80], watt[128];
    int b = blockIdx.x, t = threadIdx.x;
    int w = t >> 6, lane = t & 63;
    for (int s = w; s < 76; s += 4){
        float acc = 0.f;
        const float* op = outs + (size_t)(s+1)*16384 + (size_t)b*512;
        #pragma unroll
        for (int hh = 0; hh < 512; hh += 64) acc += op[hh+lane]*fcw[hh+lane];
        #pragma unroll
        for (int off=32; off; off>>=1) acc += __shfl_down(acc, off);
        if (lane==0) att[s] = acc + fcb[0];
    }
    __syncthreads();
    if (t < 64){
        float a0 = (t<76)? att[t] : -1e30f;
        float a1 = (t+64<76)? att[t+64] : -1e30f;
        float m = fmaxf(a0,a1);
        #pragma unroll
        for (int off=32; off; off>>=1) m = fmaxf(m, __shfl_xor(m, off));
        float e0 = (t<76)? __expf(a0-m) : 0.f;
        float e1 = (t+64<76)? __expf(a1-m) : 0.f;
        float ssum = e0+e1;
        #pragma unroll
        for (int off=32; off; off>>=1) ssum += __shfl_xor(ssum, off);
        float ri = 1.f/ssum;
        watt[t] = e0*ri;
        watt[t+64] = e1*ri;
    }
    __syncthreads();
    for (int h = t; h < 512; h += 256){
        float acc=0.f;
        for (int s=0;s<76;++s) acc += watt[s]*outs[(size_t)(s+1)*16384 + (size_t)b*512 + h];
        out[(size_t)b*512 + h] = acc;
    }
}

// ---------------- launch ----------------------------------------------------
extern "C" void kernel_launch(void* const* d_in, const int* in_sizes, int n_in,
                              void* d_out, int out_size, void* d_ws, size_t ws_size,
                              hipStream_t stream)
{
    const float* x   = (const float*)d_in[0];
    const float* w1  = (const float*)d_in[1];  const float* b1  = (const float*)d_in[2];
    const float* w2  = (const float*)d_in[3];  const float* b2  = (const float*)d_in[4];
    const float* w3  = (const float*)d_in[5];  const float* b3  = (const float*)d_in[6];
    const float* w4  = (const float*)d_in[7];  const float* b4  = (const float*)d_in[8];
    const float* wq  = (const float*)d_in[9];  const float* wk  = (const float*)d_in[10];
    const float* wv  = (const float*)d_in[11]; const float* wv1 = (const float*)d_in[12];
    const float* gamma = (const float*)d_in[13];
    const float* wih = (const float*)d_in[14]; const float* whh = (const float*)d_in[15];
    const float* bih = (const float*)d_in[16]; const float* bhh = (const float*)d_in[17];
    const float* fcw = (const float*)d_in[18]; const float* fcb = (const float*)d_in[19];

    // workspace layout (float-equivalents); total 25,161,728 fl ~= 100.6 MB
    float* ws = (float*)d_ws;
    size_t off = 0;
    unsigned short* bufAh = (unsigned short*)(ws + off); off += 1966080ull; // 2*240*8192 us
    unsigned short* bufAl = (unsigned short*)(ws + off); off += 1966080ull;
    unsigned short* bufBh = (unsigned short*)(ws + off); off += 1933312ull; // 2*236*8192 us
    unsigned short* bufBl = (unsigned short*)(ws + off); off += 1933312ull;
    float* V1b = ws + off; off += 1245184ull;                               // 152*64*128 fp32
    unsigned short* seq_bf = (unsigned short*)(ws + off); off += 9961472ull; // 2432*8192 bf16
    float* xg   = ws + off; off += 3735552ull;    // 2432*1536 fp32
    float* outs = ws + off; off += 77ull*16384;   // fp32
    float4* whh_p = (float4*)(ws + off); off += 1048576ull; // 512*512 f4
    unsigned short* wbf_h = (unsigned short*)(ws + off); off += 30720ull;   // 61440 us
    unsigned short* wbf_l = (unsigned short*)(ws + off); off += 30720ull;
    unsigned short* wr_h  = (unsigned short*)(ws + off); off += 24576ull;   // 49152 us
    unsigned short* wr_l  = (unsigned short*)(ws + off); off += 24576ull;

    // F/G/V fp32 overlay on dead bufA region during project+attend (3.74M <= 3.93M fl)
    float* Fb = (float*)bufAh;
    float* Gb = Fb + 1245184ull;
    float* Vb = Fb + 2490368ull;
    // wih_bf overlays bufA+bufB after the loop (6.29M fl needed, 7.80M avail)
    unsigned short* wih_bf = bufAh;

    repack_convw_k<<<240, 256, 0, stream>>>(w2, w3, w4, wbf_h, wbf_l);
    repack_wrep_k<<<192, 256, 0, stream>>>(wq, wk, wv, wv1, wr_h, wr_l);
    build_whhp_k<<<1024, 256, 0, stream>>>(whh, whh_p);
    hipMemsetAsync(outs, 0, 16384*sizeof(float), stream);

    for (int chunk=0; chunk<16; ++chunk){
        int b_base = chunk*2;
        conv1_k<<<240, 256, 0, stream>>>(x, bufAh, bufAl, w1, b1, b_base);
        conv_mfma_s<<<dim3(236,2), 256, 0, stream>>>(bufAh, bufAl, bufBh, bufBl,
                                                     wbf_h, wbf_l, b2, 240, 236);
        conv_mfma_s<<<dim3(232,2), 256, 0, stream>>>(bufBh, bufBl, bufAh, bufAl,
                                                     wbf_h+20480, wbf_l+20480, b3, 236, 232);
        conv_mfma_s<<<dim3(228,2), 256, 0, stream>>>(bufAh, bufAl, bufBh, bufBl,
                                                     wbf_h+40960, wbf_l+40960, b4, 232, 228);
        project_mfma_s<<<dim3(76,2,4), 256, 0, stream>>>(bufBh, bufBl, wr_h, wr_l,
                                                         Fb, Gb, Vb, V1b);
        attend_k<<<dim3(76,2), 256, 0, stream>>>(Fb, Gb, Vb, V1b, gamma, seq_bf, b_base);
    }
    conv_wih_bf16<<<12288, 256, 0, stream>>>(wih, wih_bf);
    gemm_xg_mfma<<<dim3(12,19), 256, 0, stream>>>(seq_bf, wih_bf, bih, xg);
    for (int s=0; s<76; ++s)
        gru_step_k<<<64, 256, 0, stream>>>(whh_p, xg, bhh, outs, s);
    pool_k<<<32, 256, 0, stream>>>(outs, fcw, fcb, (float*)d_out);
}

// Round 8
// 3457.112 us; speedup vs baseline: 2.8339x; 1.0661x over previous
//
#include <hip/hip_runtime.h>
#include <math.h>

// ---------------- problem constants ----------------
// B=32 in chunks of nb (adaptive: 8/4/2 by ws_size), L=244, C=128, F=64, KS=5
// conv lengths: 244 -> 240 -> 236 -> 232 -> 228 ; S=76 ; F3=192 ; D_SA=64
// HID=512, 3*HID=1536 ; big GEMM: M=2432, K=8192, N=1536
// Precision (R7-proven): conv/projection bf16 hi+lo split MFMA (fp32-accurate),
// attention fp32, seq/wih bf16. Math is bit-identical for any nb.

typedef __attribute__((ext_vector_type(8))) short short8;
typedef __attribute__((ext_vector_type(4))) float f32x4;

__device__ inline float sigm(float x){ return 1.f/(1.f+__expf(-x)); }
__device__ inline unsigned short f2bf(float f){
    unsigned int u = __float_as_uint(f);
    u = (u + 0x7FFFu + ((u >> 16) & 1u)) >> 16;
    return (unsigned short)u;
}
__device__ inline float bf2f(unsigned short h){
    return __uint_as_float(((unsigned int)h) << 16);
}

// ---------------- conv1: x[b][l][c] fp32 -> h1 pair [b][l][c][f] -----------
__global__ __launch_bounds__(256) void conv1_k(const float* __restrict__ x,
        unsigned short* __restrict__ out_h, unsigned short* __restrict__ out_l,
        const float* __restrict__ w1, const float* __restrict__ b1, int b_base)
{
    __shared__ float w1s[320];
    __shared__ float b1s[64];
    int t = threadIdx.x;
    for (int idx = t; idx < 320; idx += 256) w1s[idx] = w1[idx];
    if (t < 64)  b1s[t] = b1[t];
    __syncthreads();
    int i = blockIdx.x*256 + t;          // < nb*240*128
    int c = i & 127; int t2 = i >> 7;
    int l = t2 % 240; int b = t2 / 240;
    const float* xp = x + ((size_t)(b_base + b)*244 + l)*128 + c;
    float xv[5];
    #pragma unroll
    for (int k=0;k<5;++k) xv[k] = xp[k*128];
    unsigned short* oh = out_h + (size_t)i*64;
    unsigned short* ol = out_l + (size_t)i*64;
    #pragma unroll
    for (int f8=0; f8<8; ++f8){
        unsigned short rh[8], rl[8];
        #pragma unroll
        for (int j=0;j<8;++j){
            int f = f8*8 + j;
            float a = b1s[f];
            #pragma unroll
            for (int k=0;k<5;++k) a += w1s[f*5+k]*xv[k];
            a = a > 0.f ? a : 0.f;
            unsigned short hi = f2bf(a);
            rh[j] = hi;
            rl[j] = f2bf(a - bf2f(hi));
        }
        *(short8*)(oh + f8*8) = *(short8*)rh;
        *(short8*)(ol + f8*8) = *(short8*)rl;
    }
}

// ---------------- conv weight repack pairs: [layer][k][fo][fi] -------------
__global__ __launch_bounds__(256) void repack_convw_k(const float* __restrict__ w2,
        const float* __restrict__ w3, const float* __restrict__ w4,
        unsigned short* __restrict__ wbf_h, unsigned short* __restrict__ wbf_l)
{
    int idx = blockIdx.x*256 + threadIdx.x;   // < 61440
    int fi = idx & 63; int t2 = idx >> 6;
    int fo = t2 & 63;  int t3 = t2 >> 6;
    int k = t3 % 5;    int layer = t3 / 5;
    const float* ws_ = (layer==0)? w2 : (layer==1)? w3 : w4;
    float v = ws_[(fo*64 + fi)*5 + k];
    unsigned short hi = f2bf(v);
    wbf_h[idx] = hi;
    wbf_l[idx] = f2bf(v - bf2f(hi));
}

// ---------------- conv2/3/4 split MFMA: pairs -> pairs, relu ---------------
__global__ __launch_bounds__(256) void conv_mfma_s(
        const unsigned short* __restrict__ in_h, const unsigned short* __restrict__ in_l,
        unsigned short* __restrict__ out_h, unsigned short* __restrict__ out_l,
        const unsigned short* __restrict__ wk_h, const unsigned short* __restrict__ wk_l,
        const float* __restrict__ bias, int Lin, int Lout)
{
    __shared__ __align__(16) unsigned short Abh[128*72], Abl[128*72];
    __shared__ __align__(16) unsigned short Wbh[64*72],  Wbl[64*72];
    int t = threadIdx.x;
    int l = blockIdx.x, b = blockIdx.y;
    int lane = t & 63, w = t >> 6;
    int lr = lane & 15, lh = lane >> 4;
    f32x4 acc[2][4];
    #pragma unroll
    for (int mf=0;mf<2;++mf)
        #pragma unroll
        for (int nf=0;nf<4;++nf) acc[mf][nf] = (f32x4)0.f;

    const size_t ib = ((size_t)b*Lin + l)*8192;
    for (int k=0;k<5;++k){
        __syncthreads();
        #pragma unroll
        for (int i=0;i<4;++i){
            int idx = i*256 + t; int row = idx>>3, c8 = idx&7;
            *(short8*)&Abh[row*72 + c8*8] = *(const short8*)(in_h + ib + (size_t)k*8192 + idx*8);
            *(short8*)&Abl[row*72 + c8*8] = *(const short8*)(in_l + ib + (size_t)k*8192 + idx*8);
        }
        #pragma unroll
        for (int i=0;i<2;++i){
            int idx = i*256 + t; int row = idx>>3, c8 = idx&7;
            *(short8*)&Wbh[row*72 + c8*8] = *(const short8*)(wk_h + k*4096 + idx*8);
            *(short8*)&Wbl[row*72 + c8*8] = *(const short8*)(wk_l + k*4096 + idx*8);
        }
        __syncthreads();
        #pragma unroll
        for (int kk=0;kk<2;++kk){
            short8 ah[2], al[2], bh[4], blo[4];
            #pragma unroll
            for (int mf=0;mf<2;++mf){
                ah[mf] = *(const short8*)&Abh[(w*32+mf*16+lr)*72 + kk*32 + lh*8];
                al[mf] = *(const short8*)&Abl[(w*32+mf*16+lr)*72 + kk*32 + lh*8];
            }
            #pragma unroll
            for (int nf=0;nf<4;++nf){
                bh[nf]  = *(const short8*)&Wbh[(nf*16+lr)*72 + kk*32 + lh*8];
                blo[nf] = *(const short8*)&Wbl[(nf*16+lr)*72 + kk*32 + lh*8];
            }
            #pragma unroll
            for (int mf=0;mf<2;++mf)
                #pragma unroll
                for (int nf=0;nf<4;++nf){
                    acc[mf][nf] = __builtin_amdgcn_mfma_f32_16x16x32_bf16(ah[mf], bh[nf],  acc[mf][nf], 0,0,0);
                    acc[mf][nf] = __builtin_amdgcn_mfma_f32_16x16x32_bf16(ah[mf], blo[nf], acc[mf][nf], 0,0,0);
                    acc[mf][nf] = __builtin_amdgcn_mfma_f32_16x16x32_bf16(al[mf], bh[nf],  acc[mf][nf], 0,0,0);
                }
        }
    }
    const size_t ob = ((size_t)b*Lout + l)*8192;
    #pragma unroll
    for (int nf=0;nf<4;++nf){
        int fo = nf*16 + lr;
        float bv = bias[fo];
        #pragma unroll
        for (int mf=0;mf<2;++mf)
            #pragma unroll
            for (int q=0;q<4;++q){
                int c = w*32 + mf*16 + lh*4 + q;
                float v = acc[mf][nf][q] + bv;
                v = v > 0.f ? v : 0.f;
                unsigned short hi = f2bf(v);
                out_h[ob + c*64 + fo] = hi;
                out_l[ob + c*64 + fo] = f2bf(v - bf2f(hi));
            }
    }
}

// ---------------- attention weight repack pairs: [md][jj*64+f] -------------
__global__ __launch_bounds__(256) void repack_wrep_k(const float* __restrict__ wq,
        const float* __restrict__ wk, const float* __restrict__ wv,
        const float* __restrict__ wv1,
        unsigned short* __restrict__ wr_h, unsigned short* __restrict__ wr_l)
{
    int idx = blockIdx.x*256 + threadIdx.x;   // < 256*192
    int ko = idx % 192; int md = idx / 192;
    int m = md >> 6, d = md & 63;
    int jj = ko >> 6, f = ko & 63;
    const float* src = (m==0)? wq : (m==1)? wk : (m==2)? wv : wv1;
    float v = src[d*192 + f*3 + jj];
    unsigned short hi = f2bf(v);
    wr_h[idx] = hi;
    wr_l[idx] = f2bf(v - bf2f(hi));
}

// ---------------- projection split MFMA: per (b,s,mz) ----------------------
__global__ __launch_bounds__(256) void project_mfma_s(
        const unsigned short* __restrict__ h_h, const unsigned short* __restrict__ h_l,
        const unsigned short* __restrict__ wr_h, const unsigned short* __restrict__ wr_l,
        float* __restrict__ Fo, float* __restrict__ Go,
        float* __restrict__ Vo, float* __restrict__ V1o)
{
    __shared__ __align__(16) unsigned short Abh[128*72], Abl[128*72];
    __shared__ __align__(16) unsigned short Bbh[64*72],  Bbl[64*72];
    int t = threadIdx.x;
    int s = blockIdx.x, bl = blockIdx.y, mz = blockIdx.z;
    int lane = t & 63, w = t >> 6;
    int wm = w >> 1, wn = w & 1;
    int lr = lane & 15, lh = lane >> 4;
    f32x4 acc[4][2];
    #pragma unroll
    for (int mf=0;mf<4;++mf)
        #pragma unroll
        for (int nf=0;nf<2;++nf) acc[mf][nf] = (f32x4)0.f;

    for (int jj=0;jj<3;++jj){
        __syncthreads();
        const size_t ao_ = ((size_t)bl*228 + 3*s + jj)*8192;
        #pragma unroll
        for (int i=0;i<4;++i){
            int idx = i*256 + t; int row = idx>>3, c8 = idx&7;
            *(short8*)&Abh[row*72 + c8*8] = *(const short8*)(h_h + ao_ + idx*8);
            *(short8*)&Abl[row*72 + c8*8] = *(const short8*)(h_l + ao_ + idx*8);
        }
        #pragma unroll
        for (int i=0;i<2;++i){
            int idx = i*256 + t; int row = idx>>3, c8 = idx&7;
            size_t wo = (size_t)(mz*64 + row)*192 + jj*64 + c8*8;
            *(short8*)&Bbh[row*72 + c8*8] = *(const short8*)(wr_h + wo);
            *(short8*)&Bbl[row*72 + c8*8] = *(const short8*)(wr_l + wo);
        }
        __syncthreads();
        #pragma unroll
        for (int kk=0;kk<2;++kk){
            short8 ah[4], al[4], bh[2], blo[2];
            #pragma unroll
            for (int mf=0;mf<4;++mf){
                ah[mf] = *(const short8*)&Abh[(wm*64+mf*16+lr)*72 + kk*32 + lh*8];
                al[mf] = *(const short8*)&Abl[(wm*64+mf*16+lr)*72 + kk*32 + lh*8];
            }
            #pragma unroll
            for (int nf=0;nf<2;++nf){
                bh[nf]  = *(const short8*)&Bbh[(wn*32+nf*16+lr)*72 + kk*32 + lh*8];
                blo[nf] = *(const short8*)&Bbl[(wn*32+nf*16+lr)*72 + kk*32 + lh*8];
            }
            #pragma unroll
            for (int mf=0;mf<4;++mf)
                #pragma unroll
                for (int nf=0;nf<2;++nf){
                    acc[mf][nf] = __builtin_amdgcn_mfma_f32_16x16x32_bf16(ah[mf], bh[nf],  acc[mf][nf], 0,0,0);
                    acc[mf][nf] = __builtin_amdgcn_mfma_f32_16x16x32_bf16(ah[mf], blo[nf], acc[mf][nf], 0,0,0);
                    acc[mf][nf] = __builtin_amdgcn_mfma_f32_16x16x32_bf16(al[mf], bh[nf],  acc[mf][nf], 0,0,0);
                }
        }
    }
    float* dst = (mz==0)? Fo : (mz==1)? Go : (mz==2)? Vo : V1o;
    size_t bs = (size_t)bl*76 + s;
    #pragma unroll
    for (int mf=0;mf<4;++mf)
        #pragma unroll
        for (int nf=0;nf<2;++nf){
            int d = wn*32 + nf*16 + lr;
            int c0 = wm*64 + mf*16 + lh*4;
            *(f32x4*)&dst[(bs*64 + d)*128 + c0] = acc[mf][nf];
        }
}

// ---------------- attention, fp32, 64KB LDS (R7-proven) --------------------
__global__ __launch_bounds__(256) void attend_k(const float* __restrict__ Fg,
        const float* __restrict__ Gg, const float* __restrict__ Vg,
        const float* __restrict__ V1g, const float* __restrict__ gamma,
        unsigned short* __restrict__ seq_bf, int b_base)
{
    __shared__ float sm[16384];    // exactly 64 KB
    int t = threadIdx.x;
    int s = blockIdx.x, bl = blockIdx.y;
    size_t base = ((size_t)bl*76 + s)*8192;
    for (int i=t; i<8192; i+=256) sm[i]      = Fg[base+i];
    for (int i=t; i<8192; i+=256) sm[8192+i] = Gg[base+i];
    __syncthreads();

    int k = t & 127, ch = t >> 7;
    float sc[64];
    #pragma unroll
    for (int j=0;j<64;++j) sc[j]=0.f;
    for (int d=0; d<64; ++d){
        float gk = sm[8192 + d*128 + k];
        #pragma unroll
        for (int cj=0; cj<16; ++cj){
            float4 f4 = *(const float4*)&sm[d*128 + ch*64 + cj*4];
            sc[cj*4+0] += f4.x*gk; sc[cj*4+1] += f4.y*gk;
            sc[cj*4+2] += f4.z*gk; sc[cj*4+3] += f4.w*gk;
        }
    }
    __syncthreads();
    float m = -1e30f;
    #pragma unroll
    for (int j=0;j<64;++j) m = fmaxf(m, sc[j]);
    sm[t] = m;
    for (int i=t; i<8192; i+=256) sm[8192+i] = Vg[base+i];
    __syncthreads();
    m = fmaxf(sm[k], sm[128+k]);
    float lsum = 0.f;
    #pragma unroll
    for (int j=0;j<64;++j){ sc[j] = __expf(sc[j]-m); lsum += sc[j]; }
    __syncthreads();
    sm[t] = lsum;
    __syncthreads();
    float rinv = 1.f/(sm[k] + sm[128+k]);
    #pragma unroll
    for (int j=0;j<64;++j) sc[j] *= rinv;
    __syncthreads();

    if (ch == 0){
        #pragma unroll
        for (int j=0;j<64;++j) sm[j*128 + k] = sc[j];
    }
    __syncthreads();

    int k2 = t & 31, dq = t >> 5;
    float ao[8][4];
    #pragma unroll
    for (int j=0;j<8;++j)
        #pragma unroll
        for (int mm=0;mm<4;++mm) ao[j][mm]=0.f;

    for (int c2=0; c2<64; ++c2){
        float bv0 = sm[c2*128 + k2],    bv1 = sm[c2*128 + k2+32];
        float bv2 = sm[c2*128 + k2+64], bv3 = sm[c2*128 + k2+96];
        #pragma unroll
        for (int j=0;j<8;++j){
            float v = sm[8192 + (dq*8+j)*128 + c2];
            ao[j][0]+=v*bv0; ao[j][1]+=v*bv1; ao[j][2]+=v*bv2; ao[j][3]+=v*bv3;
        }
    }
    __syncthreads();
    if (ch == 1){
        #pragma unroll
        for (int j=0;j<64;++j) sm[j*128 + k] = sc[j];
    }
    __syncthreads();
    for (int c2=64; c2<128; ++c2){
        float bv0 = sm[(c2-64)*128 + k2],    bv1 = sm[(c2-64)*128 + k2+32];
        float bv2 = sm[(c2-64)*128 + k2+64], bv3 = sm[(c2-64)*128 + k2+96];
        #pragma unroll
        for (int j=0;j<8;++j){
            float v = sm[8192 + (dq*8+j)*128 + c2];
            ao[j][0]+=v*bv0; ao[j][1]+=v*bv1; ao[j][2]+=v*bv2; ao[j][3]+=v*bv3;
        }
    }

    float gm = gamma[0];
    size_t sbase = (size_t)(s*32 + b_base + bl)*8192;
    #pragma unroll
    for (int j=0;j<8;++j){
        int d = dq*8+j;
        #pragma unroll
        for (int mm=0;mm<4;++mm){
            int kk = k2 + 32*mm;
            float val = gm*ao[j][mm] + V1g[base + (size_t)d*128 + kk];
            seq_bf[sbase + (size_t)d*128 + kk] = f2bf(val);
        }
    }
}

// ---------------- wih -> bf16 (identity) -----------------------------------
__global__ __launch_bounds__(256) void conv_wih_bf16(const float* __restrict__ w,
        unsigned short* __restrict__ o)
{
    int i = (blockIdx.x*256 + threadIdx.x)*4;   // < 1536*8192
    float4 v = *(const float4*)&w[i];
    ushort4 r;
    r.x = f2bf(v.x); r.y = f2bf(v.y); r.z = f2bf(v.z); r.w = f2bf(v.w);
    *(ushort4*)&o[i] = r;
}

// ---------------- big GEMM bf16 MFMA: 8 waves, XCD-swizzled ----------------
// 1D grid 228 (19 m-tiles x 12 n-tiles of 128x128), BK=64, 512 threads.
__global__ __launch_bounds__(512) void gemm_xg_mfma(const unsigned short* __restrict__ A,
        const unsigned short* __restrict__ Bw, const float* __restrict__ bih,
        float* __restrict__ out)
{
    __shared__ float AsF[128*36];
    __shared__ float BsF[128*36];
    // bijective XCD swizzle (nwg=228, 8 XCDs: q=28, r=4)
    int orig = blockIdx.x;
    int xcd = orig & 7, o8 = orig >> 3;
    int wgid = (xcd < 4 ? xcd*29 : 116 + (xcd-4)*28) + o8;
    int n0 = (wgid / 19) * 128;       // n-major: co-XCD blocks share B-tile
    int m0 = (wgid % 19) * 128;

    int t = threadIdx.x;
    int w = t >> 6;                    // 0..7
    int wm = w >> 1, wn = w & 1;       // 4 x 2 wave grid; wave owns 32x64
    int lane = t & 63, lr = lane & 15, lh = lane >> 4;

    f32x4 acc[2][4];
    #pragma unroll
    for (int mi=0;mi<2;++mi)
        #pragma unroll
        for (int ni=0;ni<4;++ni) acc[mi][ni] = (f32x4)0.f;

    // staging: 1024 x 16B per tile; 512 threads x 2
    float4 ra[2], rb[2];
    #pragma unroll
    for (int i=0;i<2;++i){
        int idx = i*512 + t; int row = idx>>3, seg = idx&7;
        ra[i] = *(const float4*)(A  + (size_t)(m0 + row)*8192 + seg*8);
        rb[i] = *(const float4*)(Bw + (size_t)(n0 + row)*8192 + seg*8);
    }
    for (int kt=0; kt<128; ++kt){
        __syncthreads();
        #pragma unroll
        for (int i=0;i<2;++i){
            int idx = i*512 + t; int row = idx>>3, seg = idx&7;
            *(float4*)&AsF[row*36 + seg*4] = ra[i];
            *(float4*)&BsF[row*36 + seg*4] = rb[i];
        }
        __syncthreads();
        if (kt < 127){
            int k0 = (kt+1)*64;
            #pragma unroll
            for (int i=0;i<2;++i){
                int idx = i*512 + t; int row = idx>>3, seg = idx&7;
                ra[i] = *(const float4*)(A  + (size_t)(m0 + row)*8192 + k0 + seg*8);
                rb[i] = *(const float4*)(Bw + (size_t)(n0 + row)*8192 + k0 + seg*8);
            }
        }
        #pragma unroll
        for (int kk=0;kk<2;++kk){
            short8 af[2], bf_[4];
            #pragma unroll
            for (int mi=0;mi<2;++mi)
                af[mi] = *(short8*)&AsF[(wm*32 + mi*16 + lr)*36 + kk*16 + lh*4];
            #pragma unroll
            for (int ni=0;ni<4;++ni)
                bf_[ni] = *(short8*)&BsF[(wn*64 + ni*16 + lr)*36 + kk*16 + lh*4];
            #pragma unroll
            for (int mi=0;mi<2;++mi)
                #pragma unroll
                for (int ni=0;ni<4;++ni)
                    acc[mi][ni] = __builtin_amdgcn_mfma_f32_16x16x32_bf16(
                                      af[mi], bf_[ni], acc[mi][ni], 0, 0, 0);
        }
    }
    #pragma unroll
    for (int ni=0;ni<4;++ni){
        int n = n0 + wn*64 + ni*16 + lr;
        float bv = bih[n];
        #pragma unroll
        for (int mi=0;mi<2;++mi){
            #pragma unroll
            for (int q=0;q<4;++q){
                int m = m0 + wm*32 + mi*16 + lh*4 + q;
                out[(size_t)m*1536 + n] = acc[mi][ni][q] + bv;
            }
        }
    }
}

// ---------------- GRU weight repack ----------------------------------------
__global__ __launch_bounds__(256) void build_whhp_k(const float* __restrict__ whh,
        float4* __restrict__ whh_p)
{
    int idx = blockIdx.x*256 + threadIdx.x;   // < 512*512
    int i = idx >> 9, j = idx & 511;
    float4 o;
    o.x = whh[(size_t)j*512 + i];
    o.y = whh[(size_t)(512+j)*512 + i];
    o.z = whh[(size_t)(1024+j)*512 + i];
    o.w = 0.f;
    whh_p[idx] = o;
}

// ---------------- one GRU step (R7-proven) ---------------------------------
__global__ __launch_bounds__(256) void gru_step_k(const float4* __restrict__ whh_p,
        const float* __restrict__ xg, const float* __restrict__ bhh,
        float* __restrict__ outs, int s)
{
    __shared__ float hl[2048];
    int t = threadIdx.x;
    int jc = blockIdx.x & 7, bq = blockIdx.x >> 3;
    for (int idx=t; idx<2048; idx+=256)
        hl[idx] = outs[(size_t)s*16384 + (size_t)(bq*4 + (idx>>9))*512 + (idx&511)];
    __syncthreads();
    int j = jc*64 + (t & 63), bl_ = t >> 6, b = bq*4 + bl_;
    float a0=0.f,a1=0.f,a2=0.f;
    const float4* wp = whh_p + j;
    const float* hb = hl + bl_*512;
    #pragma unroll 4
    for (int i=0;i<512;++i){
        float4 w4 = wp[(size_t)i*512];
        float hv = hb[i];
        a0 += w4.x*hv; a1 += w4.y*hv; a2 += w4.z*hv;
    }
    size_t xi = (size_t)(s*32 + b)*1536 + j;
    float xr = xg[xi], xz = xg[xi+512], xn = xg[xi+1024];
    float hr = a0 + bhh[j], hz = a1 + bhh[512+j], hn = a2 + bhh[1024+j];
    float r = sigm(xr+hr), z = sigm(xz+hz);
    float n = tanhf(xn + r*hn);
    float hp = hb[j];
    float hnew = (1.f - z)*n + z*hp;
    outs[(size_t)(s+1)*16384 + (size_t)b*512 + j] = hnew;
}

// ---------------- final attention pooling over s ---------------------------
__global__ __launch_bounds__(256) void pool_k(const float* __restrict__ outs,
        const float* __restrict__ fcw, const float* __restrict__ fcb,
        float* __restrict__ out)
{
    __shared__ float att[80], watt[128];
    int b = blockIdx.x, t = threadIdx.x;
    int w = t >> 6, lane = t & 63;
    for (int s = w; s < 76; s += 4){
        float acc = 0.f;
        const float* op = outs + (size_t)(s+1)*16384 + (size_t)b*512;
        #pragma unroll
        for (int hh = 0; hh < 512; hh += 64) acc += op[hh+lane]*fcw[hh+lane];
        #pragma unroll
        for (int off=32; off; off>>=1) acc += __shfl_down(acc, off);
        if (lane==0) att[s] = acc + fcb[0];
    }
    __syncthreads();
    if (t < 64){
        float a0 = (t<76)? att[t] : -1e30f;
        float a1 = (t+64<76)? att[t+64] : -1e30f;
        float m = fmaxf(a0,a1);
        #pragma unroll
        for (int off=32; off; off>>=1) m = fmaxf(m, __shfl_xor(m, off));
        float e0 = (t<76)? __expf(a0-m) : 0.f;
        float e1 = (t+64<76)? __expf(a1-m) : 0.f;
        float ssum = e0+e1;
        #pragma unroll
        for (int off=32; off; off>>=1) ssum += __shfl_xor(ssum, off);
        float ri = 1.f/ssum;
        watt[t] = e0*ri;
        watt[t+64] = e1*ri;
    }
    __syncthreads();
    for (int h = t; h < 512; h += 256){
        float acc=0.f;
        for (int s=0;s<76;++s) acc += watt[s]*outs[(size_t)(s+1)*16384 + (size_t)b*512 + h];
        out[(size_t)b*512 + h] = acc;
    }
}

// ---------------- launch ----------------------------------------------------
extern "C" void kernel_launch(void* const* d_in, const int* in_sizes, int n_in,
                              void* d_out, int out_size, void* d_ws, size_t ws_size,
                              hipStream_t stream)
{
    const float* x   = (const float*)d_in[0];
    const float* w1  = (const float*)d_in[1];  const float* b1  = (const float*)d_in[2];
    const float* w2  = (const float*)d_in[3];  const float* b2  = (const float*)d_in[4];
    const float* w3  = (const float*)d_in[5];  const float* b3  = (const float*)d_in[6];
    const float* w4  = (const float*)d_in[7];  const float* b4  = (const float*)d_in[8];
    const float* wq  = (const float*)d_in[9];  const float* wk  = (const float*)d_in[10];
    const float* wv  = (const float*)d_in[11]; const float* wv1 = (const float*)d_in[12];
    const float* gamma = (const float*)d_in[13];
    const float* wih = (const float*)d_in[14]; const float* whh = (const float*)d_in[15];
    const float* bih = (const float*)d_in[16]; const float* bhh = (const float*)d_in[17];
    const float* fcw = (const float*)d_in[18]; const float* fcb = (const float*)d_in[19];

    // adaptive chunk size nb by workspace (math is bit-identical for any nb):
    // total floats = nb*4,521,984 + 16,117,760
    int nb = 2;
    if (ws_size >= (8ull*4521984ull + 16117760ull)*4ull + 4096) nb = 8;
    else if (ws_size >= (4ull*4521984ull + 16117760ull)*4ull + 4096) nb = 4;

    float* ws = (float*)d_ws;
    size_t off = 0;
    size_t szAh = (size_t)nb*983040ull;   // nb*240*8192 us in fl units
    size_t szBh = (size_t)nb*966656ull;   // nb*236*8192 us in fl units
    size_t szP  = (size_t)nb*622592ull;   // nb*76*64*128 fp32
    unsigned short* bufAh = (unsigned short*)(ws + off); off += szAh;
    unsigned short* bufAl = (unsigned short*)(ws + off); off += szAh;
    unsigned short* bufBh = (unsigned short*)(ws + off); off += szBh;
    unsigned short* bufBl = (unsigned short*)(ws + off); off += szBh;
    float* V1b = ws + off; off += szP;
    unsigned short* seq_bf = (unsigned short*)(ws + off); off += 9961472ull; // 2432*8192 bf16
    float* xg   = ws + off; off += 3735552ull;    // 2432*1536 fp32
    float* outs = ws + off; off += 77ull*16384;
    float4* whh_p = (float4*)(ws + off); off += 1048576ull;
    unsigned short* wbf_h = (unsigned short*)(ws + off); off += 30720ull;
    unsigned short* wbf_l = (unsigned short*)(ws + off); off += 30720ull;
    unsigned short* wr_h  = (unsigned short*)(ws + off); off += 24576ull;
    unsigned short* wr_l  = (unsigned short*)(ws + off); off += 24576ull;

    // F/G/V fp32 overlay on dead bufA pair (3*szP <= 2*szAh for all nb)
    float* Fb = (float*)bufAh;
    float* Gb = Fb + szP;
    float* Vb = Fb + 2*szP;
    // wih_bf overlays bufA+bufB after the loop (needs 6,291,456 fl <= 2*(szAh+szBh))
    unsigned short* wih_bf = bufAh;

    repack_convw_k<<<240, 256, 0, stream>>>(w2, w3, w4, wbf_h, wbf_l);
    repack_wrep_k<<<192, 256, 0, stream>>>(wq, wk, wv, wv1, wr_h, wr_l);
    build_whhp_k<<<1024, 256, 0, stream>>>(whh, whh_p);
    hipMemsetAsync(outs, 0, 16384*sizeof(float), stream);

    int nchunks = 32 / nb;
    for (int chunk=0; chunk<nchunks; ++chunk){
        int b_base = chunk*nb;
        conv1_k<<<nb*120, 256, 0, stream>>>(x, bufAh, bufAl, w1, b1, b_base);
        conv_mfma_s<<<dim3(236,nb), 256, 0, stream>>>(bufAh, bufAl, bufBh, bufBl,
                                                      wbf_h, wbf_l, b2, 240, 236);
        conv_mfma_s<<<dim3(232,nb), 256, 0, stream>>>(bufBh, bufBl, bufAh, bufAl,
                                                      wbf_h+20480, wbf_l+20480, b3, 236, 232);
        conv_mfma_s<<<dim3(228,nb), 256, 0, stream>>>(bufAh, bufAl, bufBh, bufBl,
                                                      wbf_h+40960, wbf_l+40960, b4, 232, 228);
        project_mfma_s<<<dim3(76,nb,4), 256, 0, stream>>>(bufBh, bufBl, wr_h, wr_l,
                                                          Fb, Gb, Vb, V1b);
        attend_k<<<dim3(76,nb), 256, 0, stream>>>(Fb, Gb, Vb, V1b, gamma, seq_bf, b_base);
    }
    conv_wih_bf16<<<12288, 256, 0, stream>>>(wih, wih_bf);
    gemm_xg_mfma<<<228, 512, 0, stream>>>(seq_bf, wih_bf, bih, xg);
    for (int s=0; s<76; ++s)
        gru_step_k<<<64, 256, 0, stream>>>(whh_p, xg, bhh, outs, s);
    pool_k<<<32, 256, 0, stream>>>(outs, fcw, fcb, (float*)d_out);
}